// Round 2
// baseline (142600.488 us; speedup 1.0000x reference)
//
#include <hip/hip_runtime.h>
#include <math.h>

#define B_SZ 128
#define T_IN 8000
#define T_OUT 1600
#define HDIM 384
#define GDIM 1536   // 4*H
#define TC 40       // time chunk
#define NCHUNK (T_OUT / TC)   // 40
#define NTILES (12 * (B_SZ * TC / 128))   // 480 gemm tiles per chunk
#define NLB 64            // LSTM blocks: 8 groups x 8 column-slices
#define NEPOCH (5 * NCHUNK)   // 200 fused dispatches per launch

typedef _Float16 f16;
typedef __attribute__((ext_vector_type(2))) _Float16 f16x2;
typedef __attribute__((ext_vector_type(4))) _Float16 f16x4;
typedef __attribute__((ext_vector_type(8))) _Float16 f16x8;

__device__ inline float fdot2(f16x2 a, f16x2 b, float c) {
#if __has_builtin(__builtin_amdgcn_fdot2)
  return __builtin_amdgcn_fdot2(a, b, c, false);
#else
  return fmaf((float)a[0], (float)b[0], fmaf((float)a[1], (float)b[1], c));
#endif
}

__device__ inline float rcp_fast(float x) {
#if __has_builtin(__builtin_amdgcn_rcpf)
  return __builtin_amdgcn_rcpf(x);
#else
  return 1.f / x;
#endif
}
__device__ inline float sigf(float z) { return rcp_fast(1.f + __expf(-z)); }
__device__ inline float tanh_fast(float z) {
  z = fminf(fmaxf(z, -15.f), 15.f);
  float e = __expf(2.f * z);
  return (e - 1.f) * rcp_fast(e + 1.f);
}

// ---------------------------------------------------------------------------
// conv1 (5,1,4) + silu + conv2 (5,4,16) + silu, fused. One thread per (b,t).
// ---------------------------------------------------------------------------
__global__ __launch_bounds__(256) void conv12_kernel(
    const float* __restrict__ x, const float* __restrict__ w1, const float* __restrict__ b1,
    const float* __restrict__ w2, const float* __restrict__ b2, f16* __restrict__ y2) {
  __shared__ float sw1[20], sb1[4], sw2[320], sb2[16];
  int tid = threadIdx.x;
  if (tid < 20) sw1[tid] = w1[tid];
  if (tid < 4)  sb1[tid] = b1[tid];
  if (tid < 16) sb2[tid] = b2[tid];
  for (int i = tid; i < 320; i += 256) sw2[i] = w2[i];
  __syncthreads();
  int flat = blockIdx.x * 256 + tid;
  int b = flat / T_IN, t = flat % T_IN;
  const float* xb = x + (size_t)b * T_IN;
  float xv[9];
#pragma unroll
  for (int d = 0; d < 9; ++d) {
    int tt = t + d - 4;
    xv[d] = (tt >= 0 && tt < T_IN) ? xb[tt] : 0.f;
  }
  float y1[5][4];
#pragma unroll
  for (int u = 0; u < 5; ++u) {
    int tau = t + u - 2;
    bool valid = (tau >= 0 && tau < T_IN);
#pragma unroll
    for (int co = 0; co < 4; ++co) {
      float a = sb1[co];
#pragma unroll
      for (int k = 0; k < 5; ++k) a = fmaf(xv[u + k], sw1[k * 4 + co], a);
      y1[u][co] = valid ? (a / (1.f + expf(-a))) : 0.f;
    }
  }
  f16x8 o0, o1;
#pragma unroll
  for (int co = 0; co < 16; ++co) {
    float a = sb2[co];
#pragma unroll
    for (int u = 0; u < 5; ++u)
#pragma unroll
      for (int ci = 0; ci < 4; ++ci)
        a = fmaf(y1[u][ci], sw2[(u * 4 + ci) * 16 + co], a);
    float sv = a / (1.f + expf(-a));
    if (co < 8) o0[co] = (f16)sv; else o1[co - 8] = (f16)sv;
  }
  f16x8* dst = (f16x8*)(y2 + (size_t)flat * 16);
  dst[0] = o0;
  dst[1] = o1;
}

// ---------------------------------------------------------------------------
// conv3: (19,16,384), stride 5, SAME (pad 7/7), + silu. fp16 in/out, fp32 math.
// ---------------------------------------------------------------------------
__global__ __launch_bounds__(384) void conv3_kernel(
    const f16* __restrict__ y2, const float* __restrict__ w3, const float* __restrict__ b3,
    f16* __restrict__ act) {
  __shared__ float in_s[94 * 16];
  int tid = threadIdx.x;
  int b = blockIdx.y;
  int t0 = blockIdx.x * 16;
  int base_t = t0 * 5 - 7;
  for (int i = tid; i < 94 * 16; i += 384) {
    int tau = i >> 4, ci = i & 15;
    int tt = base_t + tau;
    in_s[i] = (tt >= 0 && tt < T_IN) ? (float)y2[((size_t)b * T_IN + tt) * 16 + ci] : 0.f;
  }
  __syncthreads();
  int c = tid;
  float acc[16];
  float bv = b3[c];
#pragma unroll
  for (int tt = 0; tt < 16; ++tt) acc[tt] = bv;
  for (int kk = 0; kk < 19; ++kk) {
#pragma unroll
    for (int c4 = 0; c4 < 4; ++c4) {
      float wa = w3[(size_t)((kk * 16 + c4 * 4 + 0) * 384) + c];
      float wb = w3[(size_t)((kk * 16 + c4 * 4 + 1) * 384) + c];
      float wc = w3[(size_t)((kk * 16 + c4 * 4 + 2) * 384) + c];
      float wd = w3[(size_t)((kk * 16 + c4 * 4 + 3) * 384) + c];
#pragma unroll
      for (int tt = 0; tt < 16; ++tt) {
        const float4 iv = *(const float4*)&in_s[(tt * 5 + kk) * 16 + c4 * 4];
        acc[tt] = fmaf(iv.x, wa, acc[tt]);
        acc[tt] = fmaf(iv.y, wb, acc[tt]);
        acc[tt] = fmaf(iv.z, wc, acc[tt]);
        acc[tt] = fmaf(iv.w, wd, acc[tt]);
      }
    }
  }
#pragma unroll
  for (int tt = 0; tt < 16; ++tt) {
    float a = acc[tt];
    a = a / (1.f + expf(-a));
    act[((size_t)b * T_OUT + t0 + tt) * HDIM + c] = (f16)a;
  }
}

// ---------------------------------------------------------------------------
// Wh repack: whP[l][k2][c] = (Wh[l][2k2][c], Wh[l][2k2+1][c]) as fp16x2.
// ---------------------------------------------------------------------------
__global__ __launch_bounds__(256) void whcvt_kernel(
    const float* __restrict__ Wh, f16x2* __restrict__ whP) {
  size_t idx = (size_t)blockIdx.x * 256 + threadIdx.x;
  int l = (int)(idx / (192 * 1536));
  int rem = (int)(idx % (192 * 1536));
  int k2 = rem / 1536;
  int c = rem % 1536;
  const float* src = Wh + ((size_t)l * 384 + 2 * k2) * 1536 + c;
  f16x2 v;
  v[0] = (f16)src[0];
  v[1] = (f16)src[1536];
  whP[idx] = v;
}

// ---------------------------------------------------------------------------
// Standalone chunked xg GEMM (primes chunk 0 of each layer).
// ---------------------------------------------------------------------------
__global__ __launch_bounds__(256) void gemm_xg_kernel(
    const f16* __restrict__ act, const float* __restrict__ Bw,
    f16* __restrict__ C, int lo) {
  __shared__ f16x2 As2[8 * 136];
  __shared__ f16x2 Bs2[8 * 128];
  int tid = threadIdx.x;
  int n0 = blockIdx.x * 128;
  int m0 = blockIdx.y * 128;
  int am = tid >> 2;
  int ak = (tid & 3) * 4;
  int bk = tid >> 5;
  int bn = (tid & 31) * 4;
  int row0 = m0 + am, row1 = row0 + 64;
  const f16* Ap0 = act + ((size_t)(row0 / TC) * T_OUT + lo + row0 % TC) * HDIM + ak;
  const f16* Ap1 = act + ((size_t)(row1 / TC) * T_OUT + lo + row1 % TC) * HDIM + ak;
  const float* Bp = Bw + (size_t)(2 * bk) * GDIM + n0 + bn;
  f16x4 ra0 = *(const f16x4*)Ap0;
  f16x4 ra1 = *(const f16x4*)Ap1;
  float4 rb0 = *(const float4*)Bp;
  float4 rb1 = *(const float4*)(Bp + (size_t)GDIM);
  float acc[8][8];
#pragma unroll
  for (int i = 0; i < 8; ++i)
#pragma unroll
    for (int j = 0; j < 8; ++j) acc[i][j] = 0.f;
  int tx = tid & 15, ty = tid >> 4;
  for (int kt = 0; kt < 24; ++kt) {
    int ak2 = ak >> 1;
    As2[(ak2 + 0) * 136 + am] = (f16x2){ra0[0], ra0[1]};
    As2[(ak2 + 1) * 136 + am] = (f16x2){ra0[2], ra0[3]};
    As2[(ak2 + 0) * 136 + am + 64] = (f16x2){ra1[0], ra1[1]};
    As2[(ak2 + 1) * 136 + am + 64] = (f16x2){ra1[2], ra1[3]};
    Bs2[bk * 128 + bn + 0] = (f16x2){(f16)rb0.x, (f16)rb1.x};
    Bs2[bk * 128 + bn + 1] = (f16x2){(f16)rb0.y, (f16)rb1.y};
    Bs2[bk * 128 + bn + 2] = (f16x2){(f16)rb0.z, (f16)rb1.z};
    Bs2[bk * 128 + bn + 3] = (f16x2){(f16)rb0.w, (f16)rb1.w};
    __syncthreads();
    if (kt < 23) {
      Ap0 += 16; Ap1 += 16; Bp += (size_t)16 * GDIM;
      ra0 = *(const f16x4*)Ap0;
      ra1 = *(const f16x4*)Ap1;
      rb0 = *(const float4*)Bp;
      rb1 = *(const float4*)(Bp + (size_t)GDIM);
    }
#pragma unroll
    for (int k2 = 0; k2 < 8; ++k2) {
      f16x8 a0 = *(const f16x8*)&As2[k2 * 136 + ty * 4];
      f16x8 a1 = *(const f16x8*)&As2[k2 * 136 + 64 + ty * 4];
      f16x8 b0 = *(const f16x8*)&Bs2[k2 * 128 + tx * 4];
      f16x8 b1 = *(const f16x8*)&Bs2[k2 * 128 + 64 + tx * 4];
      f16x2 av[8], bv[8];
#pragma unroll
      for (int q = 0; q < 4; ++q) {
        av[q] = (f16x2){a0[2 * q], a0[2 * q + 1]};
        av[q + 4] = (f16x2){a1[2 * q], a1[2 * q + 1]};
        bv[q] = (f16x2){b0[2 * q], b0[2 * q + 1]};
        bv[q + 4] = (f16x2){b1[2 * q], b1[2 * q + 1]};
      }
#pragma unroll
      for (int i = 0; i < 8; ++i)
#pragma unroll
        for (int j = 0; j < 8; ++j) acc[i][j] = fdot2(av[i], bv[j], acc[i][j]);
    }
    __syncthreads();
  }
#pragma unroll
  for (int i = 0; i < 8; ++i) {
    int mi = (i < 4) ? (ty * 4 + i) : (64 + ty * 4 + i - 4);
    f16* Cp = C + (size_t)(m0 + mi) * GDIM + n0;
    f16x4 p0, p1;
    p0[0] = (f16)acc[i][0]; p0[1] = (f16)acc[i][1]; p0[2] = (f16)acc[i][2]; p0[3] = (f16)acc[i][3];
    p1[0] = (f16)acc[i][4]; p1[1] = (f16)acc[i][5]; p1[2] = (f16)acc[i][6]; p1[3] = (f16)acc[i][7];
    *(f16x4*)(Cp + tx * 4) = p0;
    *(f16x4*)(Cp + 64 + tx * 4) = p1;
  }
}

// ---------------------------------------------------------------------------
// FUSED kernel: 256 blocks x 768 threads.
//  blocks 0..63  : systolic LSTM. 8 groups (16 batches each) x 8 col-slices.
//    Each block owns 48 h-cols (192 z-cols across 4 gates) for its group's
//    16 batches. Weights: 48 f16x2 per thread, VGPR-resident for the whole
//    dispatch (asm-pinned). Per step: z-partials (4-way K-split reduced via
//    LDS), gates, then 48-col h slice exchanged between the group's 8 blocks
//    through a global double-buffered region using agent-scope atomics
//    (coherent-point, cross-XCD safe) + per-group step counter. No weight
//    streaming => the 8.2us/step per-CU L2-BW wall is gone.
//  blocks 64..255: GEMM for next chunk at lo_g; 3 sub-tiles/block (as r0).
// ---------------------------------------------------------------------------
union FusedSh {
  struct { f16x2 h2s[16][192]; float zsp[4][16][192]; float bias_s[192]; } L;  // 62208 B
  struct { f16x2 As2[3][8 * 136]; f16x2 Bs2[3][8 * 128]; } G;                  // 25344 B
  char pad[62464];
};

__global__ __launch_bounds__(768, 1) void fused_kernel(
    const f16* __restrict__ xgc_rd, f16* __restrict__ xgc_wr,
    const f16x2* __restrict__ whP, const float* __restrict__ bias,
    f16* __restrict__ act, float* __restrict__ cst, const float* __restrict__ Wi,
    unsigned* __restrict__ xh, unsigned* __restrict__ ctr,
    int lo_l, int lo_g, int reverse, int first, int do_gemm, int epoch) {
  __shared__ FusedSh sh;
  int tid = threadIdx.x;

  if (blockIdx.x < NLB) {
    // ================= systolic LSTM branch =================
    int wid = blockIdx.x;
    int g = wid >> 3;            // group 0..7 (16 batches)
    int isl = wid & 7;           // column slice 0..7 (48 h-cols)
    int b0 = g * 16;
    // dot-phase role: K-quarter kap, z-col cl (gate-major: cl = q*48+jj)
    int kap = tid / 192;         // 0..3 -> k2 in [kap*48, kap*48+48)
    int cl = tid - kap * 192;    // 0..191
    int q = cl / 48, jj = cl - q * 48;
    int cg = q * 384 + isl * 48 + jj;   // global z column
    // gate-phase role: (batch gb, slice-col gj)
    int gb = tid / 48;           // 0..15
    int gj = tid - gb * 48;      // 0..47
    int hcol = isl * 48 + gj;    // global h column

    if (tid < 192) sh.L.bias_s[tid] = bias[(tid / 48) * 384 + isl * 48 + (tid % 48)];

    // --- weights -> VGPR, loaded once, pinned against re-streaming ---
    f16x2 wreg[48];
    {
      const f16x2* wp = whP + (size_t)(kap * 48) * 1536 + cg;
#pragma unroll
      for (int r = 0; r < 48; ++r) wreg[r] = wp[(size_t)r * 1536];
#pragma unroll
      for (int r = 0; r < 48; ++r) asm volatile("" : "+v"(wreg[r]));
    }

    float c_reg;
    if (first) {
      c_reg = 0.f;
      ((f16x8*)&sh.L.h2s[0][0])[tid] = (f16x8){};
    } else {
      int tprev = reverse ? (lo_l + TC) : (lo_l - 1);
      c_reg = cst[(size_t)(b0 + gb) * HDIM + hcol];
      int c8 = gj * 8;  // 768 threads x 8 f16 = 16 batches x 384 cols
      *(f16x8*)((f16*)&sh.L.h2s[gb][0] + c8) =
          *(const f16x8*)(act + ((size_t)(b0 + gb) * T_OUT + tprev) * HDIM + c8);
    }
    unsigned* ctrp = ctr + (size_t)epoch * 8 + g;
    __syncthreads();

    for (int s = 0; s < TC; ++s) {
      int t = reverse ? (lo_l + TC - 1 - s) : (lo_l + s);
      int tl = t - lo_l;
      // xg prefetch (independent of h; consumed in gate phase ~2us later)
      const f16* xp = xgc_rd + ((size_t)(b0 + gb) * TC + tl) * GDIM + hcol;
      f16 x0 = xp[0], x1 = xp[384], x2 = xp[768], x3 = xp[1152];

      // --- z-partials: 48 k2 x 16 batches, weights in VGPR, h broadcast ---
      float acc[16];
#pragma unroll
      for (int b = 0; b < 16; ++b) acc[b] = 0.f;
      int k2b0 = kap * 48;
#pragma unroll
      for (int rq = 0; rq < 12; ++rq) {
#pragma unroll
        for (int half = 0; half < 2; ++half) {
          f16x8 hh[8];
#pragma unroll
          for (int b = 0; b < 8; ++b)
            hh[b] = *(const f16x8*)&sh.L.h2s[half * 8 + b][k2b0 + rq * 4];
#pragma unroll
          for (int b = 0; b < 8; ++b) {
#pragma unroll
            for (int r = 0; r < 4; ++r)
              acc[half * 8 + b] = fdot2(wreg[rq * 4 + r],
                                        (f16x2){hh[b][2 * r], hh[b][2 * r + 1]},
                                        acc[half * 8 + b]);
          }
        }
      }
#pragma unroll
      for (int b = 0; b < 16; ++b) sh.L.zsp[kap][b][cl] = acc[b];
      __syncthreads();

      // --- gates ---
      float zi = sh.L.zsp[0][gb][gj]        + sh.L.zsp[1][gb][gj]        + sh.L.zsp[2][gb][gj]        + sh.L.zsp[3][gb][gj]        + sh.L.bias_s[gj]        + (float)x0;
      float zf = sh.L.zsp[0][gb][48 + gj]   + sh.L.zsp[1][gb][48 + gj]   + sh.L.zsp[2][gb][48 + gj]   + sh.L.zsp[3][gb][48 + gj]   + sh.L.bias_s[48 + gj]   + (float)x1;
      float zg = sh.L.zsp[0][gb][96 + gj]   + sh.L.zsp[1][gb][96 + gj]   + sh.L.zsp[2][gb][96 + gj]   + sh.L.zsp[3][gb][96 + gj]   + sh.L.bias_s[96 + gj]   + (float)x2;
      float zo = sh.L.zsp[0][gb][144 + gj]  + sh.L.zsp[1][gb][144 + gj]  + sh.L.zsp[2][gb][144 + gj]  + sh.L.zsp[3][gb][144 + gj]  + sh.L.bias_s[144 + gj]  + (float)x3;
      float ig = sigf(zi), fg = sigf(zf), gv = tanh_fast(zg), og = sigf(zo);
      c_reg = fg * c_reg + ig * gv;
      float hv = og * tanh_fast(c_reg);
      f16 h16 = (f16)hv;
      act[((size_t)(b0 + gb) * T_OUT + t) * HDIM + hcol] = h16;

      if (s + 1 < TC) {
        // publish own 48-col h slice (pack pairs; even-gj lanes store u32)
        unsigned hu = (unsigned)__builtin_bit_cast(unsigned short, h16);
        unsigned hup = __shfl_down(hu, 1);
        if ((gj & 1) == 0) {
          unsigned word = hu | (hup << 16);
          __hip_atomic_store(xh + ((size_t)(s & 1) * 128 + (b0 + gb)) * 192 + (hcol >> 1),
                             word, __ATOMIC_RELAXED, __HIP_MEMORY_SCOPE_AGENT);
        }
        asm volatile("s_waitcnt vmcnt(0)" ::: "memory");  // own stores at coherent point
        __syncthreads();                                   // all threads' stores done
        if (tid == 0) {
          __hip_atomic_fetch_add(ctrp, 1u, __ATOMIC_RELAXED, __HIP_MEMORY_SCOPE_AGENT);
          unsigned tgt = 8u * (unsigned)(s + 1);
          while (__hip_atomic_load(ctrp, __ATOMIC_RELAXED, __HIP_MEMORY_SCOPE_AGENT) < tgt)
            __builtin_amdgcn_s_sleep(2);
        }
        __syncthreads();
        // gather all 8 slices (16 batches x 192 u32) into h2s
        const unsigned* xr = xh + (size_t)(s & 1) * 128 * 192;
#pragma unroll
        for (int k = 0; k < 4; ++k) {
          unsigned w = __hip_atomic_load(xr + (size_t)(b0 + 4 * k + kap) * 192 + cl,
                                         __ATOMIC_RELAXED, __HIP_MEMORY_SCOPE_AGENT);
          ((unsigned*)&sh.L.h2s[0][0])[(4 * k + kap) * 192 + cl] = w;
        }
        __syncthreads();
      }
    }
    cst[(size_t)(b0 + gb) * HDIM + hcol] = c_reg;
  } else {
    // ================= GEMM worker branch =================
    if (!do_gemm) return;
    int wid = blockIdx.x - NLB;       // 0..191
    int sub = tid >> 8;               // 0..2 (wave-uniform)
    int stid = tid & 255;
    int tileid = wid + 192 * sub;     // 0..575
    bool valid = (tileid < NTILES);
    int tclamp = valid ? tileid : 0;
    int n0 = (tclamp % 12) * 128;
    int m0 = (tclamp / 12) * 128;
    f16x2* As2 = &sh.G.As2[sub][0];
    f16x2* Bs2 = &sh.G.Bs2[sub][0];
    int am = stid >> 2;
    int ak = (stid & 3) * 4;
    int bk = stid >> 5;
    int bn = (stid & 31) * 4;
    int row0 = m0 + am, row1 = row0 + 64;
    const f16* Ap0 = act + ((size_t)(row0 / TC) * T_OUT + lo_g + row0 % TC) * HDIM + ak;
    const f16* Ap1 = act + ((size_t)(row1 / TC) * T_OUT + lo_g + row1 % TC) * HDIM + ak;
    const float* Bp = Wi + (size_t)(2 * bk) * GDIM + n0 + bn;
    f16x4 ra0 = {}, ra1 = {};
    float4 rb0 = {}, rb1 = {};
    if (valid) {
      ra0 = *(const f16x4*)Ap0;
      ra1 = *(const f16x4*)Ap1;
      rb0 = *(const float4*)Bp;
      rb1 = *(const float4*)(Bp + (size_t)GDIM);
    }
    float acc[8][8];
#pragma unroll
    for (int i = 0; i < 8; ++i)
#pragma unroll
      for (int j = 0; j < 8; ++j) acc[i][j] = 0.f;
    int tx = stid & 15, ty = stid >> 4;
    for (int kt = 0; kt < 24; ++kt) {
      if (valid) {
        int ak2 = ak >> 1;
        As2[(ak2 + 0) * 136 + am] = (f16x2){ra0[0], ra0[1]};
        As2[(ak2 + 1) * 136 + am] = (f16x2){ra0[2], ra0[3]};
        As2[(ak2 + 0) * 136 + am + 64] = (f16x2){ra1[0], ra1[1]};
        As2[(ak2 + 1) * 136 + am + 64] = (f16x2){ra1[2], ra1[3]};
        Bs2[bk * 128 + bn + 0] = (f16x2){(f16)rb0.x, (f16)rb1.x};
        Bs2[bk * 128 + bn + 1] = (f16x2){(f16)rb0.y, (f16)rb1.y};
        Bs2[bk * 128 + bn + 2] = (f16x2){(f16)rb0.z, (f16)rb1.z};
        Bs2[bk * 128 + bn + 3] = (f16x2){(f16)rb0.w, (f16)rb1.w};
      }
      __syncthreads();
      if (valid) {
        if (kt < 23) {
          Ap0 += 16; Ap1 += 16; Bp += (size_t)16 * GDIM;
          ra0 = *(const f16x4*)Ap0;
          ra1 = *(const f16x4*)Ap1;
          rb0 = *(const float4*)Bp;
          rb1 = *(const float4*)(Bp + (size_t)GDIM);
        }
#pragma unroll
        for (int k2 = 0; k2 < 8; ++k2) {
          f16x8 a0 = *(const f16x8*)&As2[k2 * 136 + ty * 4];
          f16x8 a1 = *(const f16x8*)&As2[k2 * 136 + 64 + ty * 4];
          f16x8 b0 = *(const f16x8*)&Bs2[k2 * 128 + tx * 4];
          f16x8 b1 = *(const f16x8*)&Bs2[k2 * 128 + 64 + tx * 4];
          f16x2 av[8], bv[8];
#pragma unroll
          for (int qq = 0; qq < 4; ++qq) {
            av[qq] = (f16x2){a0[2 * qq], a0[2 * qq + 1]};
            av[qq + 4] = (f16x2){a1[2 * qq], a1[2 * qq + 1]};
            bv[qq] = (f16x2){b0[2 * qq], b0[2 * qq + 1]};
            bv[qq + 4] = (f16x2){b1[2 * qq], b1[2 * qq + 1]};
          }
#pragma unroll
          for (int i = 0; i < 8; ++i)
#pragma unroll
            for (int j = 0; j < 8; ++j) acc[i][j] = fdot2(av[i], bv[j], acc[i][j]);
        }
      }
      __syncthreads();
    }
    if (valid) {
#pragma unroll
      for (int i = 0; i < 8; ++i) {
        int mi = (i < 4) ? (ty * 4 + i) : (64 + ty * 4 + i - 4);
        f16* Cp = xgc_wr + (size_t)(m0 + mi) * GDIM + n0;
        f16x4 p0, p1;
        p0[0] = (f16)acc[i][0]; p0[1] = (f16)acc[i][1]; p0[2] = (f16)acc[i][2]; p0[3] = (f16)acc[i][3];
        p1[0] = (f16)acc[i][4]; p1[1] = (f16)acc[i][5]; p1[2] = (f16)acc[i][6]; p1[3] = (f16)acc[i][7];
        *(f16x4*)(Cp + tx * 4) = p0;
        *(f16x4*)(Cp + 64 + tx * 4) = p1;
      }
    }
  }
}

// ---------------------------------------------------------------------------
// dense: out(204800,5) = h(204800,384 fp16) @ W(384,5) + b  (fp32 out)
// ---------------------------------------------------------------------------
__global__ __launch_bounds__(256) void dense_kernel(
    const f16* __restrict__ h, const float* __restrict__ dw,
    const float* __restrict__ db, float* __restrict__ out) {
  __shared__ float ws_[1920];
  __shared__ float bs[5];
  int tid = threadIdx.x;
  for (int i = tid; i < 1920; i += 256) ws_[i] = dw[i];
  if (tid < 5) bs[tid] = db[tid];
  __syncthreads();
  size_t flat = (size_t)blockIdx.x * 256 + tid;
  const f16* hp = h + flat * HDIM;
  float acc[5];
#pragma unroll
  for (int o = 0; o < 5; ++o) acc[o] = bs[o];
  for (int d = 0; d < HDIM; d += 4) {
    f16x4 hv = *(const f16x4*)(hp + d);
#pragma unroll
    for (int o = 0; o < 5; ++o) {
      acc[o] = fmaf((float)hv[0], ws_[(d + 0) * 5 + o], acc[o]);
      acc[o] = fmaf((float)hv[1], ws_[(d + 1) * 5 + o], acc[o]);
      acc[o] = fmaf((float)hv[2], ws_[(d + 2) * 5 + o], acc[o]);
      acc[o] = fmaf((float)hv[3], ws_[(d + 3) * 5 + o], acc[o]);
    }
  }
  float* op = out + flat * 5;
#pragma unroll
  for (int o = 0; o < 5; ++o) op[o] = acc[o];
}

// ---------------------------------------------------------------------------
extern "C" void kernel_launch(void* const* d_in, const int* in_sizes, int n_in,
                              void* d_out, int out_size, void* d_ws, size_t ws_size,
                              hipStream_t stream) {
  const float* x  = (const float*)d_in[0];
  const float* w1 = (const float*)d_in[1];
  const float* b1 = (const float*)d_in[2];
  const float* w2 = (const float*)d_in[3];
  const float* b2 = (const float*)d_in[4];
  const float* w3 = (const float*)d_in[5];
  const float* b3 = (const float*)d_in[6];
  const float* Wi = (const float*)d_in[7];
  const float* Wh = (const float*)d_in[8];
  const float* lb = (const float*)d_in[9];
  const float* dw = (const float*)d_in[10];
  const float* db = (const float*)d_in[11];
  float* out = (float*)d_out;
  char* ws = (char*)d_ws;

  // ws (~195.0 MB <= proven 197): act | xgcA | xgcB | whP | cst | xh | ctr
  const size_t ACT_BYTES = (size_t)B_SZ * T_OUT * HDIM * 2;   // 157.3 MB
  const size_t XGC_BYTES = (size_t)B_SZ * TC * GDIM * 2;      // 15.7 MB each
  const size_t WHP_BYTES = (size_t)5 * 192 * 1536 * 4;        // 5.9 MB
  const size_t CST_BYTES = (size_t)B_SZ * HDIM * 4;           // 196.6 KB
  const size_t XH_BYTES  = (size_t)2 * 128 * 192 * 4;         // 196.6 KB
  f16*      act  = (f16*)ws;
  f16*      xgcA = (f16*)(ws + ACT_BYTES);
  f16*      xgcB = (f16*)(ws + ACT_BYTES + XGC_BYTES);
  f16x2*    whP  = (f16x2*)(ws + ACT_BYTES + 2 * XGC_BYTES);
  float*    cst  = (float*)(ws + ACT_BYTES + 2 * XGC_BYTES + WHP_BYTES);
  unsigned* xh   = (unsigned*)(ws + ACT_BYTES + 2 * XGC_BYTES + WHP_BYTES + CST_BYTES);
  unsigned* ctr  = (unsigned*)(ws + ACT_BYTES + 2 * XGC_BYTES + WHP_BYTES + CST_BYTES + XH_BYTES);
  f16* y2 = xgcA;  // alias: consumed before xgc/whP are written

  hipMemsetAsync(ctr, 0, (size_t)NEPOCH * 8 * 4, stream);  // sync counters

  hipLaunchKernelGGL(conv12_kernel, dim3(B_SZ * T_IN / 256), dim3(256), 0, stream,
                     x, w1, b1, w2, b2, y2);
  hipLaunchKernelGGL(conv3_kernel, dim3(T_OUT / 16, B_SZ), dim3(384), 0, stream,
                     y2, w3, b3, act);
  hipLaunchKernelGGL(whcvt_kernel, dim3(5 * 192 * 1536 / 256), dim3(256), 0, stream,
                     Wh, whP);

  for (int l = 0; l < 5; ++l) {
    int rev = (l % 2 == 0) ? 1 : 0;
    const float* wi_p = Wi + (size_t)l * HDIM * GDIM;
    const f16x2* wh_p = whP + (size_t)l * 192 * 1536;
    const float* lb_p = lb + (size_t)l * GDIM;
    int lo0 = rev ? (T_OUT - TC) : 0;
    hipLaunchKernelGGL(gemm_xg_kernel, dim3(GDIM / 128, (B_SZ * TC) / 128), dim3(256), 0, stream,
                       act, wi_p, xgcA, lo0);
    for (int ci = 0; ci < NCHUNK; ++ci) {
      int lo_l = rev ? (T_OUT - (ci + 1) * TC) : (ci * TC);
      int do_gemm = (ci + 1 < NCHUNK) ? 1 : 0;
      int lo_g = do_gemm ? (rev ? (T_OUT - (ci + 2) * TC) : ((ci + 1) * TC)) : 0;
      f16* rd = (ci % 2 == 0) ? xgcA : xgcB;
      f16* wr = (ci % 2 == 0) ? xgcB : xgcA;
      int epoch = l * NCHUNK + ci;
      hipLaunchKernelGGL(fused_kernel, dim3(256), dim3(768), 0, stream,
                         rd, wr, wh_p, lb_p, act, cst, wi_p, xh, ctr,
                         lo_l, lo_g, rev, (ci == 0) ? 1 : 0, do_gemm, epoch);
    }
  }
  hipLaunchKernelGGL(dense_kernel, dim3((B_SZ * T_OUT) / 256), dim3(256), 0, stream,
                     act, dw, db, out);
}

// Round 3
// 63987.067 us; speedup vs baseline: 2.2286x; 2.2286x over previous
//
#include <hip/hip_runtime.h>
#include <math.h>

#define B_SZ 128
#define T_IN 8000
#define T_OUT 1600
#define HDIM 384
#define GDIM 1536   // 4*H
#define TC 40       // time chunk
#define NCHUNK (T_OUT / TC)   // 40
#define NTILES (12 * (B_SZ * TC / 128))   // 480 gemm tiles per chunk
#define NLB 64            // LSTM blocks: 8 groups x 8 column-slices
#define NEPOCH (5 * NCHUNK)   // 200 fused dispatches per launch

typedef _Float16 f16;
typedef __attribute__((ext_vector_type(2))) _Float16 f16x2;
typedef __attribute__((ext_vector_type(4))) _Float16 f16x4;
typedef __attribute__((ext_vector_type(8))) _Float16 f16x8;
typedef __attribute__((ext_vector_type(4))) float f32x4;

__device__ inline float fdot2(f16x2 a, f16x2 b, float c) {
#if __has_builtin(__builtin_amdgcn_fdot2)
  return __builtin_amdgcn_fdot2(a, b, c, false);
#else
  return fmaf((float)a[0], (float)b[0], fmaf((float)a[1], (float)b[1], c));
#endif
}

__device__ inline float rcp_fast(float x) {
#if __has_builtin(__builtin_amdgcn_rcpf)
  return __builtin_amdgcn_rcpf(x);
#else
  return 1.f / x;
#endif
}
__device__ inline float sigf(float z) { return rcp_fast(1.f + __expf(-z)); }
__device__ inline float tanh_fast(float z) {
  z = fminf(fmaxf(z, -15.f), 15.f);
  float e = __expf(2.f * z);
  return (e - 1.f) * rcp_fast(e + 1.f);
}

// ---------------------------------------------------------------------------
// conv1 (5,1,4) + silu + conv2 (5,4,16) + silu, fused. One thread per (b,t).
// ---------------------------------------------------------------------------
__global__ __launch_bounds__(256) void conv12_kernel(
    const float* __restrict__ x, const float* __restrict__ w1, const float* __restrict__ b1,
    const float* __restrict__ w2, const float* __restrict__ b2, f16* __restrict__ y2) {
  __shared__ float sw1[20], sb1[4], sw2[320], sb2[16];
  int tid = threadIdx.x;
  if (tid < 20) sw1[tid] = w1[tid];
  if (tid < 4)  sb1[tid] = b1[tid];
  if (tid < 16) sb2[tid] = b2[tid];
  for (int i = tid; i < 320; i += 256) sw2[i] = w2[i];
  __syncthreads();
  int flat = blockIdx.x * 256 + tid;
  int b = flat / T_IN, t = flat % T_IN;
  const float* xb = x + (size_t)b * T_IN;
  float xv[9];
#pragma unroll
  for (int d = 0; d < 9; ++d) {
    int tt = t + d - 4;
    xv[d] = (tt >= 0 && tt < T_IN) ? xb[tt] : 0.f;
  }
  float y1[5][4];
#pragma unroll
  for (int u = 0; u < 5; ++u) {
    int tau = t + u - 2;
    bool valid = (tau >= 0 && tau < T_IN);
#pragma unroll
    for (int co = 0; co < 4; ++co) {
      float a = sb1[co];
#pragma unroll
      for (int k = 0; k < 5; ++k) a = fmaf(xv[u + k], sw1[k * 4 + co], a);
      y1[u][co] = valid ? (a / (1.f + expf(-a))) : 0.f;
    }
  }
  f16x8 o0, o1;
#pragma unroll
  for (int co = 0; co < 16; ++co) {
    float a = sb2[co];
#pragma unroll
    for (int u = 0; u < 5; ++u)
#pragma unroll
      for (int ci = 0; ci < 4; ++ci)
        a = fmaf(y1[u][ci], sw2[(u * 4 + ci) * 16 + co], a);
    float sv = a / (1.f + expf(-a));
    if (co < 8) o0[co] = (f16)sv; else o1[co - 8] = (f16)sv;
  }
  f16x8* dst = (f16x8*)(y2 + (size_t)flat * 16);
  dst[0] = o0;
  dst[1] = o1;
}

// ---------------------------------------------------------------------------
// conv3: (19,16,384), stride 5, SAME (pad 7/7), + silu. fp16 in/out, fp32 math.
// ---------------------------------------------------------------------------
__global__ __launch_bounds__(384) void conv3_kernel(
    const f16* __restrict__ y2, const float* __restrict__ w3, const float* __restrict__ b3,
    f16* __restrict__ act) {
  __shared__ float in_s[94 * 16];
  int tid = threadIdx.x;
  int b = blockIdx.y;
  int t0 = blockIdx.x * 16;
  int base_t = t0 * 5 - 7;
  for (int i = tid; i < 94 * 16; i += 384) {
    int tau = i >> 4, ci = i & 15;
    int tt = base_t + tau;
    in_s[i] = (tt >= 0 && tt < T_IN) ? (float)y2[((size_t)b * T_IN + tt) * 16 + ci] : 0.f;
  }
  __syncthreads();
  int c = tid;
  float acc[16];
  float bv = b3[c];
#pragma unroll
  for (int tt = 0; tt < 16; ++tt) acc[tt] = bv;
  for (int kk = 0; kk < 19; ++kk) {
#pragma unroll
    for (int c4 = 0; c4 < 4; ++c4) {
      float wa = w3[(size_t)((kk * 16 + c4 * 4 + 0) * 384) + c];
      float wb = w3[(size_t)((kk * 16 + c4 * 4 + 1) * 384) + c];
      float wc = w3[(size_t)((kk * 16 + c4 * 4 + 2) * 384) + c];
      float wd = w3[(size_t)((kk * 16 + c4 * 4 + 3) * 384) + c];
#pragma unroll
      for (int tt = 0; tt < 16; ++tt) {
        const float4 iv = *(const float4*)&in_s[(tt * 5 + kk) * 16 + c4 * 4];
        acc[tt] = fmaf(iv.x, wa, acc[tt]);
        acc[tt] = fmaf(iv.y, wb, acc[tt]);
        acc[tt] = fmaf(iv.z, wc, acc[tt]);
        acc[tt] = fmaf(iv.w, wd, acc[tt]);
      }
    }
  }
#pragma unroll
  for (int tt = 0; tt < 16; ++tt) {
    float a = acc[tt];
    a = a / (1.f + expf(-a));
    act[((size_t)b * T_OUT + t0 + tt) * HDIM + c] = (f16)a;
  }
}

// ---------------------------------------------------------------------------
// Wh -> MFMA B-fragment repack.
// whB dword idx = ((((L*8+isl)*12+nt)*12+ks)*64 + lane)*4 + d
//   cz = nt*16 + (lane&15); gate = cz&3; jj = cz>>2;  (gate-interleaved cols)
//   gcol = gate*384 + isl*48 + jj
//   k2d = ks*16 + (lane>>4)*4 + d;  pair = (Wh[2*k2d][gcol], Wh[2*k2d+1][gcol])
// ---------------------------------------------------------------------------
__global__ __launch_bounds__(256) void whcvt_kernel(
    const float* __restrict__ Wh, f16x2* __restrict__ whB) {
  size_t idx = (size_t)blockIdx.x * 256 + threadIdx.x;
  int d = (int)(idx & 3);
  size_t r1 = idx >> 2;
  int lane = (int)(r1 & 63);
  size_t r2 = r1 >> 6;
  int ks = (int)(r2 % 12);
  size_t r3 = r2 / 12;
  int nt = (int)(r3 % 12);
  size_t r4 = r3 / 12;
  int isl = (int)(r4 & 7);
  int L = (int)(r4 >> 3);
  int cz = nt * 16 + (lane & 15);
  int gate = cz & 3;
  int jj = cz >> 2;
  int gcol = gate * 384 + isl * 48 + jj;
  int k2d = ks * 16 + (lane >> 4) * 4 + d;
  const float* src = Wh + ((size_t)L * 384 + 2 * k2d) * 1536 + gcol;
  f16x2 v;
  v[0] = (f16)src[0];
  v[1] = (f16)src[1536];
  whB[idx] = v;
}

// ---------------------------------------------------------------------------
// Standalone chunked xg GEMM (primes chunk 0 of each layer).
// ---------------------------------------------------------------------------
__global__ __launch_bounds__(256) void gemm_xg_kernel(
    const f16* __restrict__ act, const float* __restrict__ Bw,
    f16* __restrict__ C, int lo) {
  __shared__ f16x2 As2[8 * 136];
  __shared__ f16x2 Bs2[8 * 128];
  int tid = threadIdx.x;
  int n0 = blockIdx.x * 128;
  int m0 = blockIdx.y * 128;
  int am = tid >> 2;
  int ak = (tid & 3) * 4;
  int bk = tid >> 5;
  int bn = (tid & 31) * 4;
  int row0 = m0 + am, row1 = row0 + 64;
  const f16* Ap0 = act + ((size_t)(row0 / TC) * T_OUT + lo + row0 % TC) * HDIM + ak;
  const f16* Ap1 = act + ((size_t)(row1 / TC) * T_OUT + lo + row1 % TC) * HDIM + ak;
  const float* Bp = Bw + (size_t)(2 * bk) * GDIM + n0 + bn;
  f16x4 ra0 = *(const f16x4*)Ap0;
  f16x4 ra1 = *(const f16x4*)Ap1;
  float4 rb0 = *(const float4*)Bp;
  float4 rb1 = *(const float4*)(Bp + (size_t)GDIM);
  float acc[8][8];
#pragma unroll
  for (int i = 0; i < 8; ++i)
#pragma unroll
    for (int j = 0; j < 8; ++j) acc[i][j] = 0.f;
  int tx = tid & 15, ty = tid >> 4;
  for (int kt = 0; kt < 24; ++kt) {
    int ak2 = ak >> 1;
    As2[(ak2 + 0) * 136 + am] = (f16x2){ra0[0], ra0[1]};
    As2[(ak2 + 1) * 136 + am] = (f16x2){ra0[2], ra0[3]};
    As2[(ak2 + 0) * 136 + am + 64] = (f16x2){ra1[0], ra1[1]};
    As2[(ak2 + 1) * 136 + am + 64] = (f16x2){ra1[2], ra1[3]};
    Bs2[bk * 128 + bn + 0] = (f16x2){(f16)rb0.x, (f16)rb1.x};
    Bs2[bk * 128 + bn + 1] = (f16x2){(f16)rb0.y, (f16)rb1.y};
    Bs2[bk * 128 + bn + 2] = (f16x2){(f16)rb0.z, (f16)rb1.z};
    Bs2[bk * 128 + bn + 3] = (f16x2){(f16)rb0.w, (f16)rb1.w};
    __syncthreads();
    if (kt < 23) {
      Ap0 += 16; Ap1 += 16; Bp += (size_t)16 * GDIM;
      ra0 = *(const f16x4*)Ap0;
      ra1 = *(const f16x4*)Ap1;
      rb0 = *(const float4*)Bp;
      rb1 = *(const float4*)(Bp + (size_t)GDIM);
    }
#pragma unroll
    for (int k2 = 0; k2 < 8; ++k2) {
      f16x8 a0 = *(const f16x8*)&As2[k2 * 136 + ty * 4];
      f16x8 a1 = *(const f16x8*)&As2[k2 * 136 + 64 + ty * 4];
      f16x8 b0 = *(const f16x8*)&Bs2[k2 * 128 + tx * 4];
      f16x8 b1 = *(const f16x8*)&Bs2[k2 * 128 + 64 + tx * 4];
      f16x2 av[8], bv[8];
#pragma unroll
      for (int q = 0; q < 4; ++q) {
        av[q] = (f16x2){a0[2 * q], a0[2 * q + 1]};
        av[q + 4] = (f16x2){a1[2 * q], a1[2 * q + 1]};
        bv[q] = (f16x2){b0[2 * q], b0[2 * q + 1]};
        bv[q + 4] = (f16x2){b1[2 * q], b1[2 * q + 1]};
      }
#pragma unroll
      for (int i = 0; i < 8; ++i)
#pragma unroll
        for (int j = 0; j < 8; ++j) acc[i][j] = fdot2(av[i], bv[j], acc[i][j]);
    }
    __syncthreads();
  }
#pragma unroll
  for (int i = 0; i < 8; ++i) {
    int mi = (i < 4) ? (ty * 4 + i) : (64 + ty * 4 + i - 4);
    f16* Cp = C + (size_t)(m0 + mi) * GDIM + n0;
    f16x4 p0, p1;
    p0[0] = (f16)acc[i][0]; p0[1] = (f16)acc[i][1]; p0[2] = (f16)acc[i][2]; p0[3] = (f16)acc[i][3];
    p1[0] = (f16)acc[i][4]; p1[1] = (f16)acc[i][5]; p1[2] = (f16)acc[i][6]; p1[3] = (f16)acc[i][7];
    *(f16x4*)(Cp + tx * 4) = p0;
    *(f16x4*)(Cp + 64 + tx * 4) = p1;
  }
}

// ---------------------------------------------------------------------------
// FUSED kernel: 256 blocks x 768 threads.
//  blocks 0..63: systolic LSTM, MFMA dot phase. 8 groups (16 batches) x 8
//    gate-interleaved column slices (cz = jj*4+gate => every 16-col N-tile
//    holds all 4 gates of 4 h-cols; gates via quad shfl_xor butterfly, no z
//    staging). Weights = MFMA B-frags, 48 VGPR/thread, loaded once, pinned.
//    Per wave per step: 12 ds_read_b128 (A from padded h2s) + 12 mfma.
//    Cross-block h exchange: verbatim round-2 protocol (agent-scope atomics,
//    parity double-buffer, per-group epoch counter) - verified correct.
//  blocks 64..255: GEMM for next chunk at lo_g; 3 sub-tiles/block.
// ---------------------------------------------------------------------------
#define HSTR 784   // padded h2s row stride in bytes (768 data + 16 pad)

union FusedSh {
  struct { char h2s[16 * HSTR]; } L;                           // 12544 B
  struct { f16x2 As2[3][8 * 136]; f16x2 Bs2[3][8 * 128]; } G;  // 25344 B
  char pad[25600];
};

__global__ __launch_bounds__(768, 1) void fused_kernel(
    const f16* __restrict__ xgc_rd, f16* __restrict__ xgc_wr,
    const f16* __restrict__ whB, const float* __restrict__ bias,
    f16* __restrict__ act, float* __restrict__ cst, const float* __restrict__ Wi,
    unsigned* __restrict__ xh, unsigned* __restrict__ ctr,
    int lo_l, int lo_g, int reverse, int first, int do_gemm, int epoch) {
  __shared__ FusedSh sh;
  int tid = threadIdx.x;

  if (blockIdx.x < NLB) {
    // ================= systolic LSTM branch (MFMA) =================
    int wid = blockIdx.x;
    int g = wid >> 3;            // group 0..7 (16 batches)
    int isl = wid & 7;           // column slice 0..7 (48 h-cols)
    int b0 = g * 16;
    int nt = tid >> 6;           // wave id == N-tile 0..11
    int l = tid & 63;
    int bg = l >> 4;             // C-frag row group: batches bg*4..bg*4+3
    int qj = (l >> 2) & 3;       // jj offset within tile
    int gate = l & 3;
    int jj = nt * 4 + qj;        // 0..47
    int hcol = isl * 48 + jj;
    int gcol = gate * 384 + isl * 48 + jj;

    // --- B-frag weights -> 48 VGPRs, loaded once, pinned ---
    f16x8 wreg[12];
    {
      const f16x8* wp = (const f16x8*)whB + (size_t)(isl * 12 + nt) * 12 * 64 + l;
#pragma unroll
      for (int ks = 0; ks < 12; ++ks) wreg[ks] = wp[(size_t)ks * 64];
#pragma unroll
      for (int ks = 0; ks < 12; ++ks) asm volatile("" : "+v"(wreg[ks]));
    }
    float bias_own = bias[gcol];

    float c_reg[4];
    if (first) {
#pragma unroll
      for (int r = 0; r < 4; ++r) c_reg[r] = 0.f;
      for (int i = tid; i < 16 * HSTR / 16; i += 768)
        *(f16x8*)(sh.L.h2s + i * 16) = (f16x8){};
    } else {
      int tprev = reverse ? (lo_l + TC) : (lo_l - 1);
#pragma unroll
      for (int r = 0; r < 4; ++r)
        c_reg[r] = cst[(size_t)(b0 + bg * 4 + r) * HDIM + hcol];
      int flat = tid * 8;
      int bt = flat / 384, c0 = flat % 384;
      *(f16x8*)(sh.L.h2s + bt * HSTR + c0 * 2) =
          *(const f16x8*)(act + ((size_t)(b0 + bt) * T_OUT + tprev) * HDIM + c0);
    }
    unsigned* ctrp = ctr + (size_t)epoch * 8 + g;
    __syncthreads();

    const char* arow = sh.L.h2s + (l & 15) * HSTR + (l >> 4) * 16;

    for (int s = 0; s < TC; ++s) {
      int t = reverse ? (lo_l + TC - 1 - s) : (lo_l + s);
      int tl = t - lo_l;
      // xg loads (own gate/col, 4 batches) - issue early, used after mfma
      float xv[4];
      {
        const f16* xb = xgc_rd + ((size_t)(b0 + bg * 4) * TC + tl) * GDIM + gcol;
#pragma unroll
        for (int r = 0; r < 4; ++r) xv[r] = (float)xb[(size_t)r * TC * GDIM];
      }

      // --- z = h @ Wslice via MFMA (full K per wave, no reduction) ---
      f32x4 acc = {0.f, 0.f, 0.f, 0.f};
#pragma unroll
      for (int ks = 0; ks < 12; ++ks) {
        f16x8 a = *(const f16x8*)(arow + ks * 64);
        acc = __builtin_amdgcn_mfma_f32_16x16x32_f16(a, wreg[ks], acc, 0, 0, 0);
      }

      // --- gates: quad butterfly distributes all 4 gates of (jj, 4 batches) ---
      f16 h16[4];
#pragma unroll
      for (int r = 0; r < 4; ++r) {
        float a = acc[r] + xv[r] + bias_own;
        float b = __shfl_xor(a, 1);
        float cc = __shfl_xor(a, 2);
        float dd = __shfl_xor(b, 2);
        // value with gate index q comes from: own(gate), b(gate^1), cc(gate^2), dd(gate^3)
        float zi = (gate == 0) ? a : (gate == 1) ? b : (gate == 2) ? cc : dd;
        float zf = (gate == 1) ? a : (gate == 0) ? b : (gate == 3) ? cc : dd;
        float zg = (gate == 2) ? a : (gate == 3) ? b : (gate == 0) ? cc : dd;
        float zo = (gate == 3) ? a : (gate == 2) ? b : (gate == 1) ? cc : dd;
        float ig = sigf(zi), fg = sigf(zf), gv = tanh_fast(zg), og = sigf(zo);
        c_reg[r] = fg * c_reg[r] + ig * gv;
        h16[r] = (f16)(og * tanh_fast(c_reg[r]));
      }
      if (gate == 0) {
#pragma unroll
        for (int r = 0; r < 4; ++r)
          act[((size_t)(b0 + bg * 4 + r) * T_OUT + t) * HDIM + hcol] = h16[r];
      }

      if (s + 1 < TC) {
        // publish own 48-col slice (pack jj with jj+1 from lane l+4)
        unsigned hu[4], hup[4];
#pragma unroll
        for (int r = 0; r < 4; ++r) {
          hu[r] = (unsigned)__builtin_bit_cast(unsigned short, h16[r]);
          hup[r] = __shfl_down(hu[r], 4);
        }
        if ((l & 7) == 0) {  // gate==0 && jj even
#pragma unroll
          for (int r = 0; r < 4; ++r)
            __hip_atomic_store(
                xh + ((size_t)((s & 1) * 128) + b0 + bg * 4 + r) * 192 + (hcol >> 1),
                hu[r] | (hup[r] << 16), __ATOMIC_RELAXED, __HIP_MEMORY_SCOPE_AGENT);
        }
        asm volatile("s_waitcnt vmcnt(0)" ::: "memory");  // own stores at coherent point
        __syncthreads();                                   // all threads' stores done
        if (tid == 0) {
          __hip_atomic_fetch_add(ctrp, 1u, __ATOMIC_RELAXED, __HIP_MEMORY_SCOPE_AGENT);
          unsigned tgt = 8u * (unsigned)(s + 1);
          while (__hip_atomic_load(ctrp, __ATOMIC_RELAXED, __HIP_MEMORY_SCOPE_AGENT) < tgt)
            __builtin_amdgcn_s_sleep(2);
        }
        __syncthreads();
        // gather the group's full h (16 batches x 192 u32) into padded h2s
        const unsigned* xr = xh + (size_t)(s & 1) * 128 * 192;
#pragma unroll
        for (int k = 0; k < 4; ++k) {
          int flat = k * 768 + tid;
          int bt = flat / 192, w = flat % 192;
          unsigned word = __hip_atomic_load(xr + (size_t)(b0 + bt) * 192 + w,
                                            __ATOMIC_RELAXED, __HIP_MEMORY_SCOPE_AGENT);
          *(unsigned*)(sh.L.h2s + bt * HSTR + w * 4) = word;
        }
        __syncthreads();
      }
    }
    if (gate == 0) {
#pragma unroll
      for (int r = 0; r < 4; ++r)
        cst[(size_t)(b0 + bg * 4 + r) * HDIM + hcol] = c_reg[r];
    }
  } else {
    // ================= GEMM worker branch =================
    if (!do_gemm) return;
    int wid = blockIdx.x - NLB;       // 0..191
    int sub = tid >> 8;               // 0..2 (wave-uniform)
    int stid = tid & 255;
    int tileid = wid + 192 * sub;     // 0..575
    bool valid = (tileid < NTILES);
    int tclamp = valid ? tileid : 0;
    int n0 = (tclamp % 12) * 128;
    int m0 = (tclamp / 12) * 128;
    f16x2* As2 = &sh.G.As2[sub][0];
    f16x2* Bs2 = &sh.G.Bs2[sub][0];
    int am = stid >> 2;
    int ak = (stid & 3) * 4;
    int bk = stid >> 5;
    int bn = (stid & 31) * 4;
    int row0 = m0 + am, row1 = row0 + 64;
    const f16* Ap0 = act + ((size_t)(row0 / TC) * T_OUT + lo_g + row0 % TC) * HDIM + ak;
    const f16* Ap1 = act + ((size_t)(row1 / TC) * T_OUT + lo_g + row1 % TC) * HDIM + ak;
    const float* Bp = Wi + (size_t)(2 * bk) * GDIM + n0 + bn;
    f16x4 ra0 = {}, ra1 = {};
    float4 rb0 = {}, rb1 = {};
    if (valid) {
      ra0 = *(const f16x4*)Ap0;
      ra1 = *(const f16x4*)Ap1;
      rb0 = *(const float4*)Bp;
      rb1 = *(const float4*)(Bp + (size_t)GDIM);
    }
    float acc[8][8];
#pragma unroll
    for (int i = 0; i < 8; ++i)
#pragma unroll
      for (int j = 0; j < 8; ++j) acc[i][j] = 0.f;
    int tx = stid & 15, ty = stid >> 4;
    for (int kt = 0; kt < 24; ++kt) {
      if (valid) {
        int ak2 = ak >> 1;
        As2[(ak2 + 0) * 136 + am] = (f16x2){ra0[0], ra0[1]};
        As2[(ak2 + 1) * 136 + am] = (f16x2){ra0[2], ra0[3]};
        As2[(ak2 + 0) * 136 + am + 64] = (f16x2){ra1[0], ra1[1]};
        As2[(ak2 + 1) * 136 + am + 64] = (f16x2){ra1[2], ra1[3]};
        Bs2[bk * 128 + bn + 0] = (f16x2){(f16)rb0.x, (f16)rb1.x};
        Bs2[bk * 128 + bn + 1] = (f16x2){(f16)rb0.y, (f16)rb1.y};
        Bs2[bk * 128 + bn + 2] = (f16x2){(f16)rb0.z, (f16)rb1.z};
        Bs2[bk * 128 + bn + 3] = (f16x2){(f16)rb0.w, (f16)rb1.w};
      }
      __syncthreads();
      if (valid) {
        if (kt < 23) {
          Ap0 += 16; Ap1 += 16; Bp += (size_t)16 * GDIM;
          ra0 = *(const f16x4*)Ap0;
          ra1 = *(const f16x4*)Ap1;
          rb0 = *(const float4*)Bp;
          rb1 = *(const float4*)(Bp + (size_t)GDIM);
        }
#pragma unroll
        for (int k2 = 0; k2 < 8; ++k2) {
          f16x8 a0 = *(const f16x8*)&As2[k2 * 136 + ty * 4];
          f16x8 a1 = *(const f16x8*)&As2[k2 * 136 + 64 + ty * 4];
          f16x8 b0 = *(const f16x8*)&Bs2[k2 * 128 + tx * 4];
          f16x8 b1 = *(const f16x8*)&Bs2[k2 * 128 + 64 + tx * 4];
          f16x2 av[8], bv[8];
#pragma unroll
          for (int qq = 0; qq < 4; ++qq) {
            av[qq] = (f16x2){a0[2 * qq], a0[2 * qq + 1]};
            av[qq + 4] = (f16x2){a1[2 * qq], a1[2 * qq + 1]};
            bv[qq] = (f16x2){b0[2 * qq], b0[2 * qq + 1]};
            bv[qq + 4] = (f16x2){b1[2 * qq], b1[2 * qq + 1]};
          }
#pragma unroll
          for (int i = 0; i < 8; ++i)
#pragma unroll
            for (int j = 0; j < 8; ++j) acc[i][j] = fdot2(av[i], bv[j], acc[i][j]);
        }
      }
      __syncthreads();
    }
    if (valid) {
#pragma unroll
      for (int i = 0; i < 8; ++i) {
        int mi = (i < 4) ? (ty * 4 + i) : (64 + ty * 4 + i - 4);
        f16* Cp = xgc_wr + (size_t)(m0 + mi) * GDIM + n0;
        f16x4 p0, p1;
        p0[0] = (f16)acc[i][0]; p0[1] = (f16)acc[i][1]; p0[2] = (f16)acc[i][2]; p0[3] = (f16)acc[i][3];
        p1[0] = (f16)acc[i][4]; p1[1] = (f16)acc[i][5]; p1[2] = (f16)acc[i][6]; p1[3] = (f16)acc[i][7];
        *(f16x4*)(Cp + tx * 4) = p0;
        *(f16x4*)(Cp + 64 + tx * 4) = p1;
      }
    }
  }
}

// ---------------------------------------------------------------------------
// dense: out(204800,5) = h(204800,384 fp16) @ W(384,5) + b  (fp32 out)
// ---------------------------------------------------------------------------
__global__ __launch_bounds__(256) void dense_kernel(
    const f16* __restrict__ h, const float* __restrict__ dw,
    const float* __restrict__ db, float* __restrict__ out) {
  __shared__ float ws_[1920];
  __shared__ float bs[5];
  int tid = threadIdx.x;
  for (int i = tid; i < 1920; i += 256) ws_[i] = dw[i];
  if (tid < 5) bs[tid] = db[tid];
  __syncthreads();
  size_t flat = (size_t)blockIdx.x * 256 + tid;
  const f16* hp = h + flat * HDIM;
  float acc[5];
#pragma unroll
  for (int o = 0; o < 5; ++o) acc[o] = bs[o];
  for (int d = 0; d < HDIM; d += 4) {
    f16x4 hv = *(const f16x4*)(hp + d);
#pragma unroll
    for (int o = 0; o < 5; ++o) {
      acc[o] = fmaf((float)hv[0], ws_[(d + 0) * 5 + o], acc[o]);
      acc[o] = fmaf((float)hv[1], ws_[(d + 1) * 5 + o], acc[o]);
      acc[o] = fmaf((float)hv[2], ws_[(d + 2) * 5 + o], acc[o]);
      acc[o] = fmaf((float)hv[3], ws_[(d + 3) * 5 + o], acc[o]);
    }
  }
  float* op = out + flat * 5;
#pragma unroll
  for (int o = 0; o < 5; ++o) op[o] = acc[o];
}

// ---------------------------------------------------------------------------
extern "C" void kernel_launch(void* const* d_in, const int* in_sizes, int n_in,
                              void* d_out, int out_size, void* d_ws, size_t ws_size,
                              hipStream_t stream) {
  const float* x  = (const float*)d_in[0];
  const float* w1 = (const float*)d_in[1];
  const float* b1 = (const float*)d_in[2];
  const float* w2 = (const float*)d_in[3];
  const float* b2 = (const float*)d_in[4];
  const float* w3 = (const float*)d_in[5];
  const float* b3 = (const float*)d_in[6];
  const float* Wi = (const float*)d_in[7];
  const float* Wh = (const float*)d_in[8];
  const float* lb = (const float*)d_in[9];
  const float* dw = (const float*)d_in[10];
  const float* db = (const float*)d_in[11];
  float* out = (float*)d_out;
  char* ws = (char*)d_ws;

  // ws (~195.0 MB <= proven 197): act | xgcA | xgcB | whB | cst | xh | ctr
  const size_t ACT_BYTES = (size_t)B_SZ * T_OUT * HDIM * 2;   // 157.3 MB
  const size_t XGC_BYTES = (size_t)B_SZ * TC * GDIM * 2;      // 15.7 MB each
  const size_t WHB_BYTES = (size_t)5 * 8 * 12 * 12 * 64 * 16; // 5.9 MB
  const size_t CST_BYTES = (size_t)B_SZ * HDIM * 4;           // 196.6 KB
  const size_t XH_BYTES  = (size_t)2 * 128 * 192 * 4;         // 196.6 KB
  f16*      act  = (f16*)ws;
  f16*      xgcA = (f16*)(ws + ACT_BYTES);
  f16*      xgcB = (f16*)(ws + ACT_BYTES + XGC_BYTES);
  f16*      whB  = (f16*)(ws + ACT_BYTES + 2 * XGC_BYTES);
  float*    cst  = (float*)(ws + ACT_BYTES + 2 * XGC_BYTES + WHB_BYTES);
  unsigned* xh   = (unsigned*)(ws + ACT_BYTES + 2 * XGC_BYTES + WHB_BYTES + CST_BYTES);
  unsigned* ctr  = (unsigned*)(ws + ACT_BYTES + 2 * XGC_BYTES + WHB_BYTES + CST_BYTES + XH_BYTES);
  f16* y2 = xgcA;  // alias: consumed before xgc/whB are written

  hipMemsetAsync(ctr, 0, (size_t)NEPOCH * 8 * 4, stream);  // sync counters

  hipLaunchKernelGGL(conv12_kernel, dim3(B_SZ * T_IN / 256), dim3(256), 0, stream,
                     x, w1, b1, w2, b2, y2);
  hipLaunchKernelGGL(conv3_kernel, dim3(T_OUT / 16, B_SZ), dim3(384), 0, stream,
                     y2, w3, b3, act);
  hipLaunchKernelGGL(whcvt_kernel, dim3((unsigned)(WHB_BYTES / 4 / 256)), dim3(256), 0, stream,
                     Wh, (f16x2*)whB);

  for (int l = 0; l < 5; ++l) {
    int rev = (l % 2 == 0) ? 1 : 0;
    const float* wi_p = Wi + (size_t)l * HDIM * GDIM;
    const f16* wh_p = whB + (size_t)l * 8 * 12 * 12 * 64 * 8;
    const float* lb_p = lb + (size_t)l * GDIM;
    int lo0 = rev ? (T_OUT - TC) : 0;
    hipLaunchKernelGGL(gemm_xg_kernel, dim3(GDIM / 128, (B_SZ * TC) / 128), dim3(256), 0, stream,
                       act, wi_p, xgcA, lo0);
    for (int ci = 0; ci < NCHUNK; ++ci) {
      int lo_l = rev ? (T_OUT - (ci + 1) * TC) : (ci * TC);
      int do_gemm = (ci + 1 < NCHUNK) ? 1 : 0;
      int lo_g = do_gemm ? (rev ? (T_OUT - (ci + 2) * TC) : ((ci + 1) * TC)) : 0;
      f16* rd = (ci % 2 == 0) ? xgcA : xgcB;
      f16* wr = (ci % 2 == 0) ? xgcB : xgcA;
      int epoch = l * NCHUNK + ci;
      hipLaunchKernelGGL(fused_kernel, dim3(256), dim3(768), 0, stream,
                         rd, wr, wh_p, lb_p, act, cst, wi_p, xh, ctr,
                         lo_l, lo_g, rev, (ci == 0) ? 1 : 0, do_gemm, epoch);
    }
  }
  hipLaunchKernelGGL(dense_kernel, dim3((B_SZ * T_OUT) / 256), dim3(256), 0, stream,
                     act, dw, db, out);
}

// Round 4
// 36511.783 us; speedup vs baseline: 3.9056x; 1.7525x over previous
//
#include <hip/hip_runtime.h>
#include <math.h>

#define B_SZ 128
#define T_IN 8000
#define T_OUT 1600
#define HDIM 384
#define GDIM 1536   // 4*H
#define TC 40       // time chunk
#define NCHUNK (T_OUT / TC)   // 40
#define NTILES (12 * (B_SZ * TC / 128))   // 480 gemm tiles per chunk
#define NLB 64            // LSTM blocks: 8 groups x 8 column-slices
#define NEPOCH (5 * NCHUNK)   // 200 fused dispatches per launch

typedef _Float16 f16;
typedef __attribute__((ext_vector_type(2))) _Float16 f16x2;
typedef __attribute__((ext_vector_type(4))) _Float16 f16x4;
typedef __attribute__((ext_vector_type(8))) _Float16 f16x8;
typedef __attribute__((ext_vector_type(4))) float f32x4;

__device__ inline float fdot2(f16x2 a, f16x2 b, float c) {
#if __has_builtin(__builtin_amdgcn_fdot2)
  return __builtin_amdgcn_fdot2(a, b, c, false);
#else
  return fmaf((float)a[0], (float)b[0], fmaf((float)a[1], (float)b[1], c));
#endif
}

__device__ inline float rcp_fast(float x) {
#if __has_builtin(__builtin_amdgcn_rcpf)
  return __builtin_amdgcn_rcpf(x);
#else
  return 1.f / x;
#endif
}
__device__ inline float sigf(float z) { return rcp_fast(1.f + __expf(-z)); }
__device__ inline float tanh_fast(float z) {
  z = fminf(fmaxf(z, -15.f), 15.f);
  float e = __expf(2.f * z);
  return (e - 1.f) * rcp_fast(e + 1.f);
}

// ---------------------------------------------------------------------------
// conv1 (5,1,4) + silu + conv2 (5,4,16) + silu, fused. One thread per (b,t).
// ---------------------------------------------------------------------------
__global__ __launch_bounds__(256) void conv12_kernel(
    const float* __restrict__ x, const float* __restrict__ w1, const float* __restrict__ b1,
    const float* __restrict__ w2, const float* __restrict__ b2, f16* __restrict__ y2) {
  __shared__ float sw1[20], sb1[4], sw2[320], sb2[16];
  int tid = threadIdx.x;
  if (tid < 20) sw1[tid] = w1[tid];
  if (tid < 4)  sb1[tid] = b1[tid];
  if (tid < 16) sb2[tid] = b2[tid];
  for (int i = tid; i < 320; i += 256) sw2[i] = w2[i];
  __syncthreads();
  int flat = blockIdx.x * 256 + tid;
  int b = flat / T_IN, t = flat % T_IN;
  const float* xb = x + (size_t)b * T_IN;
  float xv[9];
#pragma unroll
  for (int d = 0; d < 9; ++d) {
    int tt = t + d - 4;
    xv[d] = (tt >= 0 && tt < T_IN) ? xb[tt] : 0.f;
  }
  float y1[5][4];
#pragma unroll
  for (int u = 0; u < 5; ++u) {
    int tau = t + u - 2;
    bool valid = (tau >= 0 && tau < T_IN);
#pragma unroll
    for (int co = 0; co < 4; ++co) {
      float a = sb1[co];
#pragma unroll
      for (int k = 0; k < 5; ++k) a = fmaf(xv[u + k], sw1[k * 4 + co], a);
      y1[u][co] = valid ? (a / (1.f + expf(-a))) : 0.f;
    }
  }
  f16x8 o0, o1;
#pragma unroll
  for (int co = 0; co < 16; ++co) {
    float a = sb2[co];
#pragma unroll
    for (int u = 0; u < 5; ++u)
#pragma unroll
      for (int ci = 0; ci < 4; ++ci)
        a = fmaf(y1[u][ci], sw2[(u * 4 + ci) * 16 + co], a);
    float sv = a / (1.f + expf(-a));
    if (co < 8) o0[co] = (f16)sv; else o1[co - 8] = (f16)sv;
  }
  f16x8* dst = (f16x8*)(y2 + (size_t)flat * 16);
  dst[0] = o0;
  dst[1] = o1;
}

// ---------------------------------------------------------------------------
// conv3: (19,16,384), stride 5, SAME (pad 7/7), + silu. fp16 in/out, fp32 math.
// ---------------------------------------------------------------------------
__global__ __launch_bounds__(384) void conv3_kernel(
    const f16* __restrict__ y2, const float* __restrict__ w3, const float* __restrict__ b3,
    f16* __restrict__ act) {
  __shared__ float in_s[94 * 16];
  int tid = threadIdx.x;
  int b = blockIdx.y;
  int t0 = blockIdx.x * 16;
  int base_t = t0 * 5 - 7;
  for (int i = tid; i < 94 * 16; i += 384) {
    int tau = i >> 4, ci = i & 15;
    int tt = base_t + tau;
    in_s[i] = (tt >= 0 && tt < T_IN) ? (float)y2[((size_t)b * T_IN + tt) * 16 + ci] : 0.f;
  }
  __syncthreads();
  int c = tid;
  float acc[16];
  float bv = b3[c];
#pragma unroll
  for (int tt = 0; tt < 16; ++tt) acc[tt] = bv;
  for (int kk = 0; kk < 19; ++kk) {
#pragma unroll
    for (int c4 = 0; c4 < 4; ++c4) {
      float wa = w3[(size_t)((kk * 16 + c4 * 4 + 0) * 384) + c];
      float wb = w3[(size_t)((kk * 16 + c4 * 4 + 1) * 384) + c];
      float wc = w3[(size_t)((kk * 16 + c4 * 4 + 2) * 384) + c];
      float wd = w3[(size_t)((kk * 16 + c4 * 4 + 3) * 384) + c];
#pragma unroll
      for (int tt = 0; tt < 16; ++tt) {
        const float4 iv = *(const float4*)&in_s[(tt * 5 + kk) * 16 + c4 * 4];
        acc[tt] = fmaf(iv.x, wa, acc[tt]);
        acc[tt] = fmaf(iv.y, wb, acc[tt]);
        acc[tt] = fmaf(iv.z, wc, acc[tt]);
        acc[tt] = fmaf(iv.w, wd, acc[tt]);
      }
    }
  }
#pragma unroll
  for (int tt = 0; tt < 16; ++tt) {
    float a = acc[tt];
    a = a / (1.f + expf(-a));
    act[((size_t)b * T_OUT + t0 + tt) * HDIM + c] = (f16)a;
  }
}

// ---------------------------------------------------------------------------
// Wh -> MFMA B-fragment repack.
// whB dword idx = ((((L*8+isl)*12+nt)*12+ks)*64 + lane)*4 + d
//   cz = nt*16 + (lane&15); gate = cz&3; jj = cz>>2;  (gate-interleaved cols)
//   gcol = gate*384 + isl*48 + jj
//   k2d = ks*16 + (lane>>4)*4 + d;  pair = (Wh[2*k2d][gcol], Wh[2*k2d+1][gcol])
// ---------------------------------------------------------------------------
__global__ __launch_bounds__(256) void whcvt_kernel(
    const float* __restrict__ Wh, f16x2* __restrict__ whB) {
  size_t idx = (size_t)blockIdx.x * 256 + threadIdx.x;
  int d = (int)(idx & 3);
  size_t r1 = idx >> 2;
  int lane = (int)(r1 & 63);
  size_t r2 = r1 >> 6;
  int ks = (int)(r2 % 12);
  size_t r3 = r2 / 12;
  int nt = (int)(r3 % 12);
  size_t r4 = r3 / 12;
  int isl = (int)(r4 & 7);
  int L = (int)(r4 >> 3);
  int cz = nt * 16 + (lane & 15);
  int gate = cz & 3;
  int jj = cz >> 2;
  int gcol = gate * 384 + isl * 48 + jj;
  int k2d = ks * 16 + (lane >> 4) * 4 + d;
  const float* src = Wh + ((size_t)L * 384 + 2 * k2d) * 1536 + gcol;
  f16x2 v;
  v[0] = (f16)src[0];
  v[1] = (f16)src[1536];
  whB[idx] = v;
}

// ---------------------------------------------------------------------------
// Standalone chunked xg GEMM (primes chunk 0 of each layer).
// ---------------------------------------------------------------------------
__global__ __launch_bounds__(256) void gemm_xg_kernel(
    const f16* __restrict__ act, const float* __restrict__ Bw,
    f16* __restrict__ C, int lo) {
  __shared__ f16x2 As2[8 * 136];
  __shared__ f16x2 Bs2[8 * 128];
  int tid = threadIdx.x;
  int n0 = blockIdx.x * 128;
  int m0 = blockIdx.y * 128;
  int am = tid >> 2;
  int ak = (tid & 3) * 4;
  int bk = tid >> 5;
  int bn = (tid & 31) * 4;
  int row0 = m0 + am, row1 = row0 + 64;
  const f16* Ap0 = act + ((size_t)(row0 / TC) * T_OUT + lo + row0 % TC) * HDIM + ak;
  const f16* Ap1 = act + ((size_t)(row1 / TC) * T_OUT + lo + row1 % TC) * HDIM + ak;
  const float* Bp = Bw + (size_t)(2 * bk) * GDIM + n0 + bn;
  f16x4 ra0 = *(const f16x4*)Ap0;
  f16x4 ra1 = *(const f16x4*)Ap1;
  float4 rb0 = *(const float4*)Bp;
  float4 rb1 = *(const float4*)(Bp + (size_t)GDIM);
  float acc[8][8];
#pragma unroll
  for (int i = 0; i < 8; ++i)
#pragma unroll
    for (int j = 0; j < 8; ++j) acc[i][j] = 0.f;
  int tx = tid & 15, ty = tid >> 4;
  for (int kt = 0; kt < 24; ++kt) {
    int ak2 = ak >> 1;
    As2[(ak2 + 0) * 136 + am] = (f16x2){ra0[0], ra0[1]};
    As2[(ak2 + 1) * 136 + am] = (f16x2){ra0[2], ra0[3]};
    As2[(ak2 + 0) * 136 + am + 64] = (f16x2){ra1[0], ra1[1]};
    As2[(ak2 + 1) * 136 + am + 64] = (f16x2){ra1[2], ra1[3]};
    Bs2[bk * 128 + bn + 0] = (f16x2){(f16)rb0.x, (f16)rb1.x};
    Bs2[bk * 128 + bn + 1] = (f16x2){(f16)rb0.y, (f16)rb1.y};
    Bs2[bk * 128 + bn + 2] = (f16x2){(f16)rb0.z, (f16)rb1.z};
    Bs2[bk * 128 + bn + 3] = (f16x2){(f16)rb0.w, (f16)rb1.w};
    __syncthreads();
    if (kt < 23) {
      Ap0 += 16; Ap1 += 16; Bp += (size_t)16 * GDIM;
      ra0 = *(const f16x4*)Ap0;
      ra1 = *(const f16x4*)Ap1;
      rb0 = *(const float4*)Bp;
      rb1 = *(const float4*)(Bp + (size_t)GDIM);
    }
#pragma unroll
    for (int k2 = 0; k2 < 8; ++k2) {
      f16x8 a0 = *(const f16x8*)&As2[k2 * 136 + ty * 4];
      f16x8 a1 = *(const f16x8*)&As2[k2 * 136 + 64 + ty * 4];
      f16x8 b0 = *(const f16x8*)&Bs2[k2 * 128 + tx * 4];
      f16x8 b1 = *(const f16x8*)&Bs2[k2 * 128 + 64 + tx * 4];
      f16x2 av[8], bv[8];
#pragma unroll
      for (int q = 0; q < 4; ++q) {
        av[q] = (f16x2){a0[2 * q], a0[2 * q + 1]};
        av[q + 4] = (f16x2){a1[2 * q], a1[2 * q + 1]};
        bv[q] = (f16x2){b0[2 * q], b0[2 * q + 1]};
        bv[q + 4] = (f16x2){b1[2 * q], b1[2 * q + 1]};
      }
#pragma unroll
      for (int i = 0; i < 8; ++i)
#pragma unroll
        for (int j = 0; j < 8; ++j) acc[i][j] = fdot2(av[i], bv[j], acc[i][j]);
    }
    __syncthreads();
  }
#pragma unroll
  for (int i = 0; i < 8; ++i) {
    int mi = (i < 4) ? (ty * 4 + i) : (64 + ty * 4 + i - 4);
    f16* Cp = C + (size_t)(m0 + mi) * GDIM + n0;
    f16x4 p0, p1;
    p0[0] = (f16)acc[i][0]; p0[1] = (f16)acc[i][1]; p0[2] = (f16)acc[i][2]; p0[3] = (f16)acc[i][3];
    p1[0] = (f16)acc[i][4]; p1[1] = (f16)acc[i][5]; p1[2] = (f16)acc[i][6]; p1[3] = (f16)acc[i][7];
    *(f16x4*)(Cp + tx * 4) = p0;
    *(f16x4*)(Cp + 64 + tx * 4) = p1;
  }
}

// ---------------------------------------------------------------------------
// FUSED kernel: 256 blocks x 768 threads.
//  blocks 0..63: systolic LSTM, MFMA dot phase (round-3 dataflow, verified).
//    Changes this round (protocol only):
//      - group = wid&7, slice = wid>>3 => a group's 8 blocks share blockIdx%8
//        (heuristically same XCD).
//      - atomic-RMW counter replaced by per-block monotonic flag tags
//        (tag = epoch*TC+s+1); all waves poll the group's 8-flag cache line.
//      - act stores moved out of the vmcnt(0) window (after flag store).
//      - next-step xg prefetch issued during the poll phase.
//  blocks 64..255: GEMM for next chunk at lo_g; 3 sub-tiles/block.
// ---------------------------------------------------------------------------
#define HSTR 784   // padded h2s row stride in bytes (768 data + 16 pad)

union FusedSh {
  struct { char h2s[16 * HSTR]; } L;                           // 12544 B
  struct { f16x2 As2[3][8 * 136]; f16x2 Bs2[3][8 * 128]; } G;  // 25344 B
  char pad[25600];
};

__global__ __launch_bounds__(768, 1) void fused_kernel(
    const f16* __restrict__ xgc_rd, f16* __restrict__ xgc_wr,
    const f16* __restrict__ whB, const float* __restrict__ bias,
    f16* __restrict__ act, float* __restrict__ cst, const float* __restrict__ Wi,
    unsigned* __restrict__ xh, unsigned* __restrict__ flg,
    int lo_l, int lo_g, int reverse, int first, int do_gemm, int epoch) {
  __shared__ FusedSh sh;
  int tid = threadIdx.x;

  if (blockIdx.x < NLB) {
    // ================= systolic LSTM branch (MFMA) =================
    int wid = blockIdx.x;
    int g = wid & 7;             // group 0..7 (16 batches) - XCD-local blocks
    int isl = wid >> 3;          // column slice 0..7 (48 h-cols)
    int b0 = g * 16;
    int nt = tid >> 6;           // wave id == N-tile 0..11
    int l = tid & 63;
    int bg = l >> 4;             // C-frag row group: batches bg*4..bg*4+3
    int qj = (l >> 2) & 3;       // jj offset within tile
    int gate = l & 3;
    int jj = nt * 4 + qj;        // 0..47
    int hcol = isl * 48 + jj;
    int gcol = gate * 384 + isl * 48 + jj;

    // --- B-frag weights -> 48 VGPRs, loaded once, pinned ---
    f16x8 wreg[12];
    {
      const f16x8* wp = (const f16x8*)whB + (size_t)(isl * 12 + nt) * 12 * 64 + l;
#pragma unroll
      for (int ks = 0; ks < 12; ++ks) wreg[ks] = wp[(size_t)ks * 64];
#pragma unroll
      for (int ks = 0; ks < 12; ++ks) asm volatile("" : "+v"(wreg[ks]));
    }
    float bias_own = bias[gcol];

    float c_reg[4];
    if (first) {
#pragma unroll
      for (int r = 0; r < 4; ++r) c_reg[r] = 0.f;
      for (int i = tid; i < 16 * HSTR / 16; i += 768)
        *(f16x8*)(sh.L.h2s + i * 16) = (f16x8){};
    } else {
      int tprev = reverse ? (lo_l + TC) : (lo_l - 1);
#pragma unroll
      for (int r = 0; r < 4; ++r)
        c_reg[r] = cst[(size_t)(b0 + bg * 4 + r) * HDIM + hcol];
      int flat = tid * 8;
      int bt = flat / 384, c0 = flat % 384;
      *(f16x8*)(sh.L.h2s + bt * HSTR + c0 * 2) =
          *(const f16x8*)(act + ((size_t)(b0 + bt) * T_OUT + tprev) * HDIM + c0);
    }
    unsigned* flgp = flg + g * 8 + isl;          // own flag
    const unsigned* pollp = flg + g * 8 + (l & 7);  // this lane's poll target
    __syncthreads();

    const char* arow = sh.L.h2s + (l & 15) * HSTR + (l >> 4) * 16;

    // xg preload for step 0
    float xv[4];
    {
      int tl0 = reverse ? (TC - 1) : 0;
      const f16* xb = xgc_rd + ((size_t)(b0 + bg * 4) * TC + tl0) * GDIM + gcol;
#pragma unroll
      for (int r = 0; r < 4; ++r) xv[r] = (float)xb[(size_t)r * TC * GDIM];
    }

    for (int s = 0; s < TC; ++s) {
      int t = reverse ? (lo_l + TC - 1 - s) : (lo_l + s);

      // --- z = h @ Wslice via MFMA (full K per wave, no reduction) ---
      f32x4 acc = {0.f, 0.f, 0.f, 0.f};
#pragma unroll
      for (int ks = 0; ks < 12; ++ks) {
        f16x8 a = *(const f16x8*)(arow + ks * 64);
        acc = __builtin_amdgcn_mfma_f32_16x16x32_f16(a, wreg[ks], acc, 0, 0, 0);
      }

      // --- gates: quad butterfly distributes all 4 gates of (jj, 4 batches) ---
      f16 h16[4];
#pragma unroll
      for (int r = 0; r < 4; ++r) {
        float a = acc[r] + xv[r] + bias_own;
        float b = __shfl_xor(a, 1);
        float cc = __shfl_xor(a, 2);
        float dd = __shfl_xor(b, 2);
        float zi = (gate == 0) ? a : (gate == 1) ? b : (gate == 2) ? cc : dd;
        float zf = (gate == 1) ? a : (gate == 0) ? b : (gate == 3) ? cc : dd;
        float zg = (gate == 2) ? a : (gate == 3) ? b : (gate == 0) ? cc : dd;
        float zo = (gate == 3) ? a : (gate == 2) ? b : (gate == 1) ? cc : dd;
        float ig = sigf(zi), fg = sigf(zf), gv = tanh_fast(zg), og = sigf(zo);
        c_reg[r] = fg * c_reg[r] + ig * gv;
        h16[r] = (f16)(og * tanh_fast(c_reg[r]));
      }

      if (s + 1 < TC) {
        // --- publish own 48-col slice FIRST (pack jj with jj+1 from lane l+4)
        unsigned hu[4], hup[4];
#pragma unroll
        for (int r = 0; r < 4; ++r) {
          hu[r] = (unsigned)__builtin_bit_cast(unsigned short, h16[r]);
          hup[r] = __shfl_down(hu[r], 4);
        }
        if ((l & 7) == 0) {  // gate==0 && jj even
#pragma unroll
          for (int r = 0; r < 4; ++r)
            __hip_atomic_store(
                xh + ((size_t)((s & 1) * 128) + b0 + bg * 4 + r) * 192 + (hcol >> 1),
                hu[r] | (hup[r] << 16), __ATOMIC_RELAXED, __HIP_MEMORY_SCOPE_AGENT);
        }
        asm volatile("s_waitcnt vmcnt(0)" ::: "memory");  // publish at coherent point
        __syncthreads();                                   // all lanes' publishes done
        unsigned tag = (unsigned)(epoch * TC + s + 1);
        if (tid == 0)
          __hip_atomic_store(flgp, tag, __ATOMIC_RELAXED, __HIP_MEMORY_SCOPE_AGENT);

        // --- hidden under poll: act store + next-step xg prefetch ---
        if (gate == 0) {
#pragma unroll
          for (int r = 0; r < 4; ++r)
            act[((size_t)(b0 + bg * 4 + r) * T_OUT + t) * HDIM + hcol] = h16[r];
        }
        {
          int tl_n = reverse ? (TC - 2 - s) : (s + 1);
          const f16* xb = xgc_rd + ((size_t)(b0 + bg * 4) * TC + tl_n) * GDIM + gcol;
#pragma unroll
          for (int r = 0; r < 4; ++r) xv[r] = (float)xb[(size_t)r * TC * GDIM];
        }

        // --- all waves poll the group's 8-flag line ---
        while (true) {
          unsigned v = __hip_atomic_load(pollp, __ATOMIC_RELAXED, __HIP_MEMORY_SCOPE_AGENT);
          if (__all(v >= tag)) break;
          __builtin_amdgcn_s_sleep(1);
        }

        // --- gather the group's full h (16 batches x 192 u32) into padded h2s
        const unsigned* xr = xh + (size_t)(s & 1) * 128 * 192;
#pragma unroll
        for (int k = 0; k < 4; ++k) {
          int flat = k * 768 + tid;
          int bt = flat / 192, w = flat % 192;
          unsigned word = __hip_atomic_load(xr + (size_t)(b0 + bt) * 192 + w,
                                            __ATOMIC_RELAXED, __HIP_MEMORY_SCOPE_AGENT);
          *(unsigned*)(sh.L.h2s + bt * HSTR + w * 4) = word;
        }
        __syncthreads();
      } else {
        if (gate == 0) {
#pragma unroll
          for (int r = 0; r < 4; ++r)
            act[((size_t)(b0 + bg * 4 + r) * T_OUT + t) * HDIM + hcol] = h16[r];
        }
      }
    }
    if (gate == 0) {
#pragma unroll
      for (int r = 0; r < 4; ++r)
        cst[(size_t)(b0 + bg * 4 + r) * HDIM + hcol] = c_reg[r];
    }
  } else {
    // ================= GEMM worker branch =================
    if (!do_gemm) return;
    int wid = blockIdx.x - NLB;       // 0..191
    int sub = tid >> 8;               // 0..2 (wave-uniform)
    int stid = tid & 255;
    int tileid = wid + 192 * sub;     // 0..575
    bool valid = (tileid < NTILES);
    int tclamp = valid ? tileid : 0;
    int n0 = (tclamp % 12) * 128;
    int m0 = (tclamp / 12) * 128;
    f16x2* As2 = &sh.G.As2[sub][0];
    f16x2* Bs2 = &sh.G.Bs2[sub][0];
    int am = stid >> 2;
    int ak = (stid & 3) * 4;
    int bk = stid >> 5;
    int bn = (stid & 31) * 4;
    int row0 = m0 + am, row1 = row0 + 64;
    const f16* Ap0 = act + ((size_t)(row0 / TC) * T_OUT + lo_g + row0 % TC) * HDIM + ak;
    const f16* Ap1 = act + ((size_t)(row1 / TC) * T_OUT + lo_g + row1 % TC) * HDIM + ak;
    const float* Bp = Wi + (size_t)(2 * bk) * GDIM + n0 + bn;
    f16x4 ra0 = {}, ra1 = {};
    float4 rb0 = {}, rb1 = {};
    if (valid) {
      ra0 = *(const f16x4*)Ap0;
      ra1 = *(const f16x4*)Ap1;
      rb0 = *(const float4*)Bp;
      rb1 = *(const float4*)(Bp + (size_t)GDIM);
    }
    float acc[8][8];
#pragma unroll
    for (int i = 0; i < 8; ++i)
#pragma unroll
      for (int j = 0; j < 8; ++j) acc[i][j] = 0.f;
    int tx = stid & 15, ty = stid >> 4;
    for (int kt = 0; kt < 24; ++kt) {
      if (valid) {
        int ak2 = ak >> 1;
        As2[(ak2 + 0) * 136 + am] = (f16x2){ra0[0], ra0[1]};
        As2[(ak2 + 1) * 136 + am] = (f16x2){ra0[2], ra0[3]};
        As2[(ak2 + 0) * 136 + am + 64] = (f16x2){ra1[0], ra1[1]};
        As2[(ak2 + 1) * 136 + am + 64] = (f16x2){ra1[2], ra1[3]};
        Bs2[bk * 128 + bn + 0] = (f16x2){(f16)rb0.x, (f16)rb1.x};
        Bs2[bk * 128 + bn + 1] = (f16x2){(f16)rb0.y, (f16)rb1.y};
        Bs2[bk * 128 + bn + 2] = (f16x2){(f16)rb0.z, (f16)rb1.z};
        Bs2[bk * 128 + bn + 3] = (f16x2){(f16)rb0.w, (f16)rb1.w};
      }
      __syncthreads();
      if (valid) {
        if (kt < 23) {
          Ap0 += 16; Ap1 += 16; Bp += (size_t)16 * GDIM;
          ra0 = *(const f16x4*)Ap0;
          ra1 = *(const f16x4*)Ap1;
          rb0 = *(const float4*)Bp;
          rb1 = *(const float4*)(Bp + (size_t)GDIM);
        }
#pragma unroll
        for (int k2 = 0; k2 < 8; ++k2) {
          f16x8 a0 = *(const f16x8*)&As2[k2 * 136 + ty * 4];
          f16x8 a1 = *(const f16x8*)&As2[k2 * 136 + 64 + ty * 4];
          f16x8 b0 = *(const f16x8*)&Bs2[k2 * 128 + tx * 4];
          f16x8 b1 = *(const f16x8*)&Bs2[k2 * 128 + 64 + tx * 4];
          f16x2 av[8], bv[8];
#pragma unroll
          for (int qq = 0; qq < 4; ++qq) {
            av[qq] = (f16x2){a0[2 * qq], a0[2 * qq + 1]};
            av[qq + 4] = (f16x2){a1[2 * qq], a1[2 * qq + 1]};
            bv[qq] = (f16x2){b0[2 * qq], b0[2 * qq + 1]};
            bv[qq + 4] = (f16x2){b1[2 * qq], b1[2 * qq + 1]};
          }
#pragma unroll
          for (int i = 0; i < 8; ++i)
#pragma unroll
            for (int j = 0; j < 8; ++j) acc[i][j] = fdot2(av[i], bv[j], acc[i][j]);
        }
      }
      __syncthreads();
    }
    if (valid) {
#pragma unroll
      for (int i = 0; i < 8; ++i) {
        int mi = (i < 4) ? (ty * 4 + i) : (64 + ty * 4 + i - 4);
        f16* Cp = xgc_wr + (size_t)(m0 + mi) * GDIM + n0;
        f16x4 p0, p1;
        p0[0] = (f16)acc[i][0]; p0[1] = (f16)acc[i][1]; p0[2] = (f16)acc[i][2]; p0[3] = (f16)acc[i][3];
        p1[0] = (f16)acc[i][4]; p1[1] = (f16)acc[i][5]; p1[2] = (f16)acc[i][6]; p1[3] = (f16)acc[i][7];
        *(f16x4*)(Cp + tx * 4) = p0;
        *(f16x4*)(Cp + 64 + tx * 4) = p1;
      }
    }
  }
}

// ---------------------------------------------------------------------------
// dense: out(204800,5) = h(204800,384 fp16) @ W(384,5) + b  (fp32 out)
// ---------------------------------------------------------------------------
__global__ __launch_bounds__(256) void dense_kernel(
    const f16* __restrict__ h, const float* __restrict__ dw,
    const float* __restrict__ db, float* __restrict__ out) {
  __shared__ float ws_[1920];
  __shared__ float bs[5];
  int tid = threadIdx.x;
  for (int i = tid; i < 1920; i += 256) ws_[i] = dw[i];
  if (tid < 5) bs[tid] = db[tid];
  __syncthreads();
  size_t flat = (size_t)blockIdx.x * 256 + tid;
  const f16* hp = h + flat * HDIM;
  float acc[5];
#pragma unroll
  for (int o = 0; o < 5; ++o) acc[o] = bs[o];
  for (int d = 0; d < HDIM; d += 4) {
    f16x4 hv = *(const f16x4*)(hp + d);
#pragma unroll
    for (int o = 0; o < 5; ++o) {
      acc[o] = fmaf((float)hv[0], ws_[(d + 0) * 5 + o], acc[o]);
      acc[o] = fmaf((float)hv[1], ws_[(d + 1) * 5 + o], acc[o]);
      acc[o] = fmaf((float)hv[2], ws_[(d + 2) * 5 + o], acc[o]);
      acc[o] = fmaf((float)hv[3], ws_[(d + 3) * 5 + o], acc[o]);
    }
  }
  float* op = out + flat * 5;
#pragma unroll
  for (int o = 0; o < 5; ++o) op[o] = acc[o];
}

// ---------------------------------------------------------------------------
extern "C" void kernel_launch(void* const* d_in, const int* in_sizes, int n_in,
                              void* d_out, int out_size, void* d_ws, size_t ws_size,
                              hipStream_t stream) {
  const float* x  = (const float*)d_in[0];
  const float* w1 = (const float*)d_in[1];
  const float* b1 = (const float*)d_in[2];
  const float* w2 = (const float*)d_in[3];
  const float* b2 = (const float*)d_in[4];
  const float* w3 = (const float*)d_in[5];
  const float* b3 = (const float*)d_in[6];
  const float* Wi = (const float*)d_in[7];
  const float* Wh = (const float*)d_in[8];
  const float* lb = (const float*)d_in[9];
  const float* dw = (const float*)d_in[10];
  const float* db = (const float*)d_in[11];
  float* out = (float*)d_out;
  char* ws = (char*)d_ws;

  // ws (~195.0 MB <= proven 197): act | xgcA | xgcB | whB | cst | xh | flg
  const size_t ACT_BYTES = (size_t)B_SZ * T_OUT * HDIM * 2;   // 157.3 MB
  const size_t XGC_BYTES = (size_t)B_SZ * TC * GDIM * 2;      // 15.7 MB each
  const size_t WHB_BYTES = (size_t)5 * 8 * 12 * 12 * 64 * 16; // 5.9 MB
  const size_t CST_BYTES = (size_t)B_SZ * HDIM * 4;           // 196.6 KB
  const size_t XH_BYTES  = (size_t)2 * 128 * 192 * 4;         // 196.6 KB
  f16*      act  = (f16*)ws;
  f16*      xgcA = (f16*)(ws + ACT_BYTES);
  f16*      xgcB = (f16*)(ws + ACT_BYTES + XGC_BYTES);
  f16*      whB  = (f16*)(ws + ACT_BYTES + 2 * XGC_BYTES);
  float*    cst  = (float*)(ws + ACT_BYTES + 2 * XGC_BYTES + WHB_BYTES);
  unsigned* xh   = (unsigned*)(ws + ACT_BYTES + 2 * XGC_BYTES + WHB_BYTES + CST_BYTES);
  unsigned* flg  = (unsigned*)(ws + ACT_BYTES + 2 * XGC_BYTES + WHB_BYTES + CST_BYTES + XH_BYTES);
  f16* y2 = xgcA;  // alias: consumed before xgc/whB are written

  hipMemsetAsync(flg, 0, 64 * sizeof(unsigned), stream);  // monotonic tag flags

  hipLaunchKernelGGL(conv12_kernel, dim3(B_SZ * T_IN / 256), dim3(256), 0, stream,
                     x, w1, b1, w2, b2, y2);
  hipLaunchKernelGGL(conv3_kernel, dim3(T_OUT / 16, B_SZ), dim3(384), 0, stream,
                     y2, w3, b3, act);
  hipLaunchKernelGGL(whcvt_kernel, dim3((unsigned)(WHB_BYTES / 4 / 256)), dim3(256), 0, stream,
                     Wh, (f16x2*)whB);

  for (int l = 0; l < 5; ++l) {
    int rev = (l % 2 == 0) ? 1 : 0;
    const float* wi_p = Wi + (size_t)l * HDIM * GDIM;
    const f16* wh_p = whB + (size_t)l * 8 * 12 * 12 * 64 * 8;
    const float* lb_p = lb + (size_t)l * GDIM;
    int lo0 = rev ? (T_OUT - TC) : 0;
    hipLaunchKernelGGL(gemm_xg_kernel, dim3(GDIM / 128, (B_SZ * TC) / 128), dim3(256), 0, stream,
                       act, wi_p, xgcA, lo0);
    for (int ci = 0; ci < NCHUNK; ++ci) {
      int lo_l = rev ? (T_OUT - (ci + 1) * TC) : (ci * TC);
      int do_gemm = (ci + 1 < NCHUNK) ? 1 : 0;
      int lo_g = do_gemm ? (rev ? (T_OUT - (ci + 2) * TC) : ((ci + 1) * TC)) : 0;
      f16* rd = (ci % 2 == 0) ? xgcA : xgcB;
      f16* wr = (ci % 2 == 0) ? xgcB : xgcA;
      int epoch = l * NCHUNK + ci;
      hipLaunchKernelGGL(fused_kernel, dim3(256), dim3(768), 0, stream,
                         rd, wr, wh_p, lb_p, act, cst, wi_p, xh, flg,
                         lo_l, lo_g, rev, (ci == 0) ? 1 : 0, do_gemm, epoch);
    }
  }
  hipLaunchKernelGGL(dense_kernel, dim3((B_SZ * T_OUT) / 256), dim3(256), 0, stream,
                     act, dw, db, out);
}

// Round 5
// 27734.360 us; speedup vs baseline: 5.1417x; 1.3165x over previous
//
#include <hip/hip_runtime.h>
#include <math.h>

#define B_SZ 128
#define T_IN 8000
#define T_OUT 1600
#define HDIM 384
#define GDIM 1536   // 4*H
#define TC 40       // time chunk
#define NCHUNK (T_OUT / TC)   // 40
#define NTILES (12 * (B_SZ * TC / 128))   // 480 gemm tiles per chunk
#define NLB 64            // LSTM blocks: 8 groups x 8 column-slices

typedef _Float16 f16;
typedef __attribute__((ext_vector_type(2))) _Float16 f16x2;
typedef __attribute__((ext_vector_type(4))) _Float16 f16x4;
typedef __attribute__((ext_vector_type(8))) _Float16 f16x8;
typedef __attribute__((ext_vector_type(4))) float f32x4;
typedef __attribute__((ext_vector_type(4))) unsigned int u32x4;

__device__ inline float fdot2(f16x2 a, f16x2 b, float c) {
#if __has_builtin(__builtin_amdgcn_fdot2)
  return __builtin_amdgcn_fdot2(a, b, c, false);
#else
  return fmaf((float)a[0], (float)b[0], fmaf((float)a[1], (float)b[1], c));
#endif
}

__device__ inline float rcp_fast(float x) {
#if __has_builtin(__builtin_amdgcn_rcpf)
  return __builtin_amdgcn_rcpf(x);
#else
  return 1.f / x;
#endif
}
__device__ inline float sigf(float z) { return rcp_fast(1.f + __expf(-z)); }
__device__ inline float tanh_fast(float z) {
  z = fminf(fmaxf(z, -15.f), 15.f);
  float e = __expf(2.f * z);
  return (e - 1.f) * rcp_fast(e + 1.f);
}

// ---------------------------------------------------------------------------
// conv1 (5,1,4) + silu + conv2 (5,4,16) + silu, fused. One thread per (b,t).
// ---------------------------------------------------------------------------
__global__ __launch_bounds__(256) void conv12_kernel(
    const float* __restrict__ x, const float* __restrict__ w1, const float* __restrict__ b1,
    const float* __restrict__ w2, const float* __restrict__ b2, f16* __restrict__ y2) {
  __shared__ float sw1[20], sb1[4], sw2[320], sb2[16];
  int tid = threadIdx.x;
  if (tid < 20) sw1[tid] = w1[tid];
  if (tid < 4)  sb1[tid] = b1[tid];
  if (tid < 16) sb2[tid] = b2[tid];
  for (int i = tid; i < 320; i += 256) sw2[i] = w2[i];
  __syncthreads();
  int flat = blockIdx.x * 256 + tid;
  int b = flat / T_IN, t = flat % T_IN;
  const float* xb = x + (size_t)b * T_IN;
  float xv[9];
#pragma unroll
  for (int d = 0; d < 9; ++d) {
    int tt = t + d - 4;
    xv[d] = (tt >= 0 && tt < T_IN) ? xb[tt] : 0.f;
  }
  float y1[5][4];
#pragma unroll
  for (int u = 0; u < 5; ++u) {
    int tau = t + u - 2;
    bool valid = (tau >= 0 && tau < T_IN);
#pragma unroll
    for (int co = 0; co < 4; ++co) {
      float a = sb1[co];
#pragma unroll
      for (int k = 0; k < 5; ++k) a = fmaf(xv[u + k], sw1[k * 4 + co], a);
      y1[u][co] = valid ? (a / (1.f + expf(-a))) : 0.f;
    }
  }
  f16x8 o0, o1;
#pragma unroll
  for (int co = 0; co < 16; ++co) {
    float a = sb2[co];
#pragma unroll
    for (int u = 0; u < 5; ++u)
#pragma unroll
      for (int ci = 0; ci < 4; ++ci)
        a = fmaf(y1[u][ci], sw2[(u * 4 + ci) * 16 + co], a);
    float sv = a / (1.f + expf(-a));
    if (co < 8) o0[co] = (f16)sv; else o1[co - 8] = (f16)sv;
  }
  f16x8* dst = (f16x8*)(y2 + (size_t)flat * 16);
  dst[0] = o0;
  dst[1] = o1;
}

// ---------------------------------------------------------------------------
// conv3: (19,16,384), stride 5, SAME (pad 7/7), + silu. fp16 in/out, fp32 math.
// ---------------------------------------------------------------------------
__global__ __launch_bounds__(384) void conv3_kernel(
    const f16* __restrict__ y2, const float* __restrict__ w3, const float* __restrict__ b3,
    f16* __restrict__ act) {
  __shared__ float in_s[94 * 16];
  int tid = threadIdx.x;
  int b = blockIdx.y;
  int t0 = blockIdx.x * 16;
  int base_t = t0 * 5 - 7;
  for (int i = tid; i < 94 * 16; i += 384) {
    int tau = i >> 4, ci = i & 15;
    int tt = base_t + tau;
    in_s[i] = (tt >= 0 && tt < T_IN) ? (float)y2[((size_t)b * T_IN + tt) * 16 + ci] : 0.f;
  }
  __syncthreads();
  int c = tid;
  float acc[16];
  float bv = b3[c];
#pragma unroll
  for (int tt = 0; tt < 16; ++tt) acc[tt] = bv;
  for (int kk = 0; kk < 19; ++kk) {
#pragma unroll
    for (int c4 = 0; c4 < 4; ++c4) {
      float wa = w3[(size_t)((kk * 16 + c4 * 4 + 0) * 384) + c];
      float wb = w3[(size_t)((kk * 16 + c4 * 4 + 1) * 384) + c];
      float wc = w3[(size_t)((kk * 16 + c4 * 4 + 2) * 384) + c];
      float wd = w3[(size_t)((kk * 16 + c4 * 4 + 3) * 384) + c];
#pragma unroll
      for (int tt = 0; tt < 16; ++tt) {
        const float4 iv = *(const float4*)&in_s[(tt * 5 + kk) * 16 + c4 * 4];
        acc[tt] = fmaf(iv.x, wa, acc[tt]);
        acc[tt] = fmaf(iv.y, wb, acc[tt]);
        acc[tt] = fmaf(iv.z, wc, acc[tt]);
        acc[tt] = fmaf(iv.w, wd, acc[tt]);
      }
    }
  }
#pragma unroll
  for (int tt = 0; tt < 16; ++tt) {
    float a = acc[tt];
    a = a / (1.f + expf(-a));
    act[((size_t)b * T_OUT + t0 + tt) * HDIM + c] = (f16)a;
  }
}

// ---------------------------------------------------------------------------
// Wh -> MFMA B-fragment repack.
// whB dword idx = ((((L*8+isl)*12+nt)*12+ks)*64 + lane)*4 + d
//   cz = nt*16 + (lane&15); gate = cz&3; jj = cz>>2;  (gate-interleaved cols)
//   gcol = gate*384 + isl*48 + jj
//   k2d = ks*16 + (lane>>4)*4 + d;  pair = (Wh[2*k2d][gcol], Wh[2*k2d+1][gcol])
// ---------------------------------------------------------------------------
__global__ __launch_bounds__(256) void whcvt_kernel(
    const float* __restrict__ Wh, f16x2* __restrict__ whB) {
  size_t idx = (size_t)blockIdx.x * 256 + threadIdx.x;
  int d = (int)(idx & 3);
  size_t r1 = idx >> 2;
  int lane = (int)(r1 & 63);
  size_t r2 = r1 >> 6;
  int ks = (int)(r2 % 12);
  size_t r3 = r2 / 12;
  int nt = (int)(r3 % 12);
  size_t r4 = r3 / 12;
  int isl = (int)(r4 & 7);
  int L = (int)(r4 >> 3);
  int cz = nt * 16 + (lane & 15);
  int gate = cz & 3;
  int jj = cz >> 2;
  int gcol = gate * 384 + isl * 48 + jj;
  int k2d = ks * 16 + (lane >> 4) * 4 + d;
  const float* src = Wh + ((size_t)L * 384 + 2 * k2d) * 1536 + gcol;
  f16x2 v;
  v[0] = (f16)src[0];
  v[1] = (f16)src[1536];
  whB[idx] = v;
}

// ---------------------------------------------------------------------------
// Standalone chunked xg GEMM (primes chunk 0 of each layer).
// ---------------------------------------------------------------------------
__global__ __launch_bounds__(256) void gemm_xg_kernel(
    const f16* __restrict__ act, const float* __restrict__ Bw,
    f16* __restrict__ C, int lo) {
  __shared__ f16x2 As2[8 * 136];
  __shared__ f16x2 Bs2[8 * 128];
  int tid = threadIdx.x;
  int n0 = blockIdx.x * 128;
  int m0 = blockIdx.y * 128;
  int am = tid >> 2;
  int ak = (tid & 3) * 4;
  int bk = tid >> 5;
  int bn = (tid & 31) * 4;
  int row0 = m0 + am, row1 = row0 + 64;
  const f16* Ap0 = act + ((size_t)(row0 / TC) * T_OUT + lo + row0 % TC) * HDIM + ak;
  const f16* Ap1 = act + ((size_t)(row1 / TC) * T_OUT + lo + row1 % TC) * HDIM + ak;
  const float* Bp = Bw + (size_t)(2 * bk) * GDIM + n0 + bn;
  f16x4 ra0 = *(const f16x4*)Ap0;
  f16x4 ra1 = *(const f16x4*)Ap1;
  float4 rb0 = *(const float4*)Bp;
  float4 rb1 = *(const float4*)(Bp + (size_t)GDIM);
  float acc[8][8];
#pragma unroll
  for (int i = 0; i < 8; ++i)
#pragma unroll
    for (int j = 0; j < 8; ++j) acc[i][j] = 0.f;
  int tx = tid & 15, ty = tid >> 4;
  for (int kt = 0; kt < 24; ++kt) {
    int ak2 = ak >> 1;
    As2[(ak2 + 0) * 136 + am] = (f16x2){ra0[0], ra0[1]};
    As2[(ak2 + 1) * 136 + am] = (f16x2){ra0[2], ra0[3]};
    As2[(ak2 + 0) * 136 + am + 64] = (f16x2){ra1[0], ra1[1]};
    As2[(ak2 + 1) * 136 + am + 64] = (f16x2){ra1[2], ra1[3]};
    Bs2[bk * 128 + bn + 0] = (f16x2){(f16)rb0.x, (f16)rb1.x};
    Bs2[bk * 128 + bn + 1] = (f16x2){(f16)rb0.y, (f16)rb1.y};
    Bs2[bk * 128 + bn + 2] = (f16x2){(f16)rb0.z, (f16)rb1.z};
    Bs2[bk * 128 + bn + 3] = (f16x2){(f16)rb0.w, (f16)rb1.w};
    __syncthreads();
    if (kt < 23) {
      Ap0 += 16; Ap1 += 16; Bp += (size_t)16 * GDIM;
      ra0 = *(const f16x4*)Ap0;
      ra1 = *(const f16x4*)Ap1;
      rb0 = *(const float4*)Bp;
      rb1 = *(const float4*)(Bp + (size_t)GDIM);
    }
#pragma unroll
    for (int k2 = 0; k2 < 8; ++k2) {
      f16x8 a0 = *(const f16x8*)&As2[k2 * 136 + ty * 4];
      f16x8 a1 = *(const f16x8*)&As2[k2 * 136 + 64 + ty * 4];
      f16x8 b0 = *(const f16x8*)&Bs2[k2 * 128 + tx * 4];
      f16x8 b1 = *(const f16x8*)&Bs2[k2 * 128 + 64 + tx * 4];
      f16x2 av[8], bv[8];
#pragma unroll
      for (int q = 0; q < 4; ++q) {
        av[q] = (f16x2){a0[2 * q], a0[2 * q + 1]};
        av[q + 4] = (f16x2){a1[2 * q], a1[2 * q + 1]};
        bv[q] = (f16x2){b0[2 * q], b0[2 * q + 1]};
        bv[q + 4] = (f16x2){b1[2 * q], b1[2 * q + 1]};
      }
#pragma unroll
      for (int i = 0; i < 8; ++i)
#pragma unroll
        for (int j = 0; j < 8; ++j) acc[i][j] = fdot2(av[i], bv[j], acc[i][j]);
    }
    __syncthreads();
  }
#pragma unroll
  for (int i = 0; i < 8; ++i) {
    int mi = (i < 4) ? (ty * 4 + i) : (64 + ty * 4 + i - 4);
    f16* Cp = C + (size_t)(m0 + mi) * GDIM + n0;
    f16x4 p0, p1;
    p0[0] = (f16)acc[i][0]; p0[1] = (f16)acc[i][1]; p0[2] = (f16)acc[i][2]; p0[3] = (f16)acc[i][3];
    p1[0] = (f16)acc[i][4]; p1[1] = (f16)acc[i][5]; p1[2] = (f16)acc[i][6]; p1[3] = (f16)acc[i][7];
    *(f16x4*)(Cp + tx * 4) = p0;
    *(f16x4*)(Cp + 64 + tx * 4) = p1;
  }
}

// ---------------------------------------------------------------------------
// FUSED kernel: 256 blocks x 768 threads.
//  blocks 0..63: systolic LSTM, MFMA dot phase (round-3/4 dataflow, verified).
//    Exchange protocol this round: TAG-IN-PAYLOAD single-RTT units.
//    xh = u32[2][128 batch][64 unit][4]: each 16B unit = 3 h-pair words +
//    monotonic tag (epoch*TC+s+1), written by ONE global_store_dwordx4
//    sc0 sc1 (16B single-instruction store: no tearing at LLC) and read by
//    ONE global_load_dwordx4 sc0 sc1 that is poll AND gather: fresh tag
//    implies the 12B in the same unit are fresh. No vmcnt(0) drain, no
//    separate flag, one less barrier. Own-slice units copied via LDS.
//  blocks 64..255: GEMM for next chunk at lo_g; 3 sub-tiles/block.
// ---------------------------------------------------------------------------
#define HSTR 784   // padded h2s row stride in bytes (768 data + 16 pad)

union FusedSh {
  struct { char h2s[16 * HSTR]; unsigned pub[16 * 25]; } L;    // 12544+1600 B
  struct { f16x2 As2[3][8 * 136]; f16x2 Bs2[3][8 * 128]; } G;  // 25344 B
  char pad[25600];
};

__global__ __launch_bounds__(768, 1) void fused_kernel(
    const f16* __restrict__ xgc_rd, f16* __restrict__ xgc_wr,
    const f16* __restrict__ whB, const float* __restrict__ bias,
    f16* __restrict__ act, float* __restrict__ cst, const float* __restrict__ Wi,
    unsigned* __restrict__ xh,
    int lo_l, int lo_g, int reverse, int first, int do_gemm, int epoch) {
  __shared__ FusedSh sh;
  int tid = threadIdx.x;

  if (blockIdx.x < NLB) {
    // ================= systolic LSTM branch (MFMA) =================
    int wid = blockIdx.x;
    int g = wid & 7;             // group 0..7 (16 batches) - XCD-local blocks
    int isl = wid >> 3;          // column slice 0..7 (48 h-cols)
    int b0 = g * 16;
    int nt = tid >> 6;           // wave id == N-tile 0..11
    int l = tid & 63;
    int bg = l >> 4;             // C-frag row group: batches bg*4..bg*4+3
    int qj = (l >> 2) & 3;       // jj offset within tile
    int gate = l & 3;
    int jj = nt * 4 + qj;        // 0..47
    int hcol = isl * 48 + jj;
    int gcol = gate * 384 + isl * 48 + jj;

    // --- B-frag weights -> 48 VGPRs, loaded once, pinned ---
    f16x8 wreg[12];
    {
      const f16x8* wp = (const f16x8*)whB + (size_t)(isl * 12 + nt) * 12 * 64 + l;
#pragma unroll
      for (int ks = 0; ks < 12; ++ks) wreg[ks] = wp[(size_t)ks * 64];
#pragma unroll
      for (int ks = 0; ks < 12; ++ks) asm volatile("" : "+v"(wreg[ks]));
    }
    float bias_own = bias[gcol];

    float c_reg[4];
    if (first) {
#pragma unroll
      for (int r = 0; r < 4; ++r) c_reg[r] = 0.f;
      for (int i = tid; i < 16 * HSTR / 16; i += 768)
        *(f16x8*)(sh.L.h2s + i * 16) = (f16x8){};
    } else {
      int tprev = reverse ? (lo_l + TC) : (lo_l - 1);
#pragma unroll
      for (int r = 0; r < 4; ++r)
        c_reg[r] = cst[(size_t)(b0 + bg * 4 + r) * HDIM + hcol];
      int flat = tid * 8;
      int bt = flat / 384, c0 = flat % 384;
      *(f16x8*)(sh.L.h2s + bt * HSTR + c0 * 2) =
          *(const f16x8*)(act + ((size_t)(b0 + bt) * T_OUT + tprev) * HDIM + c0);
    }
    __syncthreads();

    const char* arow = sh.L.h2s + (l & 15) * HSTR + (l >> 4) * 16;
    unsigned short* pubh = (unsigned short*)sh.L.pub;

    // second gather unit (1024 units over 768 threads, spread across waves)
    int k2 = (tid % 3 == 0) ? (768 + tid / 3) : -1;

    // xg preload for step 0
    float xv[4];
    {
      int tl0 = reverse ? (TC - 1) : 0;
      const f16* xb = xgc_rd + ((size_t)(b0 + bg * 4) * TC + tl0) * GDIM + gcol;
#pragma unroll
      for (int r = 0; r < 4; ++r) xv[r] = (float)xb[(size_t)r * TC * GDIM];
    }

    for (int s = 0; s < TC; ++s) {
      int t = reverse ? (lo_l + TC - 1 - s) : (lo_l + s);

      // --- z = h @ Wslice via MFMA (full K per wave, no reduction) ---
      f32x4 acc = {0.f, 0.f, 0.f, 0.f};
#pragma unroll
      for (int ks = 0; ks < 12; ++ks) {
        f16x8 a = *(const f16x8*)(arow + ks * 64);
        acc = __builtin_amdgcn_mfma_f32_16x16x32_f16(a, wreg[ks], acc, 0, 0, 0);
      }

      // --- gates: quad butterfly distributes all 4 gates of (jj, 4 batches) ---
      f16 h16[4];
#pragma unroll
      for (int r = 0; r < 4; ++r) {
        float a = acc[r] + xv[r] + bias_own;
        float b = __shfl_xor(a, 1);
        float cc = __shfl_xor(a, 2);
        float dd = __shfl_xor(b, 2);
        float zi = (gate == 0) ? a : (gate == 1) ? b : (gate == 2) ? cc : dd;
        float zf = (gate == 1) ? a : (gate == 0) ? b : (gate == 3) ? cc : dd;
        float zg = (gate == 2) ? a : (gate == 3) ? b : (gate == 0) ? cc : dd;
        float zo = (gate == 3) ? a : (gate == 2) ? b : (gate == 1) ? cc : dd;
        float ig = sigf(zi), fg = sigf(zf), gv = tanh_fast(zg), og = sigf(zo);
        c_reg[r] = fg * c_reg[r] + ig * gv;
        h16[r] = (f16)(og * tanh_fast(c_reg[r]));
      }

      if (s + 1 < TC) {
        unsigned tag = (unsigned)(epoch * TC + s + 1);
        unsigned* slotbase = xh + (size_t)(s & 1) * 128 * 256;

        // --- stage own h slice into LDS pub (rows=batch, 24 pair-words) ---
        if (gate == 0) {
          int lcol = nt * 4 + qj;
#pragma unroll
          for (int r = 0; r < 4; ++r)
            pubh[(bg * 4 + r) * 50 + lcol] = __builtin_bit_cast(unsigned short, h16[r]);
        }
        __syncthreads();  // barrier A: pub staged (MFMA h2s reads also done)

        // --- publish: 128 threads x one 16B unit (3 data words + tag) ---
        if (tid < 128) {
          int bt = tid >> 3, u = tid & 7;
          const unsigned* pw = sh.L.pub + bt * 25 + u * 3;
          u32x4 dnew;
          dnew[0] = pw[0]; dnew[1] = pw[1]; dnew[2] = pw[2]; dnew[3] = tag;
          u32x4* dp = (u32x4*)(slotbase + (((size_t)(b0 + bt) * 64) + isl * 8 + u) * 4);
          asm volatile("global_store_dwordx4 %0, %1, off sc0 sc1"
                       :: "v"(dp), "v"(dnew) : "memory");
        }

        // --- hidden under flight: act store + next-step xg prefetch ---
        if (gate == 0) {
#pragma unroll
          for (int r = 0; r < 4; ++r)
            act[((size_t)(b0 + bg * 4 + r) * T_OUT + t) * HDIM + hcol] = h16[r];
        }
        {
          int tl_n = reverse ? (TC - 2 - s) : (s + 1);
          const f16* xb = xgc_rd + ((size_t)(b0 + bg * 4) * TC + tl_n) * GDIM + gcol;
#pragma unroll
          for (int r = 0; r < 4; ++r) xv[r] = (float)xb[(size_t)r * TC * GDIM];
        }

        // --- poll-gather: tag-checked dwordx4 units -> h2s ---
        const u32x4* upA = nullptr; const u32x4* upB = nullptr;
        unsigned* dstA = nullptr; unsigned* dstB = nullptr;
#pragma unroll
        for (int uu = 0; uu < 2; ++uu) {
          int k = (uu == 0) ? tid : k2;
          if (uu == 1 && k < 0) break;
          int bt = k >> 6, rem = k & 63;
          int isl_src = rem >> 3, u = rem & 7;
          unsigned* dst = (unsigned*)(sh.L.h2s + bt * HSTR + isl_src * 96 + u * 12);
          if (isl_src == isl) {
            const unsigned* pw = sh.L.pub + bt * 25 + u * 3;
            dst[0] = pw[0]; dst[1] = pw[1]; dst[2] = pw[2];
          } else {
            const u32x4* up = (const u32x4*)(slotbase + (((size_t)(b0 + bt) * 64) + rem) * 4);
            if (!upA) { upA = up; dstA = dst; } else { upB = up; dstB = dst; }
          }
        }
        if (upA && !upB) {
          u32x4 v;
          while (true) {
            asm volatile("global_load_dwordx4 %0, %1, off sc0 sc1\n\ts_waitcnt vmcnt(0)"
                         : "=v"(v) : "v"(upA) : "memory");
            if (v[3] >= tag) break;
            __builtin_amdgcn_s_sleep(1);
          }
          dstA[0] = v[0]; dstA[1] = v[1]; dstA[2] = v[2];
        } else if (upA && upB) {
          u32x4 v0, v1;
          while (true) {
            asm volatile("global_load_dwordx4 %0, %2, off sc0 sc1\n\t"
                         "global_load_dwordx4 %1, %3, off sc0 sc1\n\t"
                         "s_waitcnt vmcnt(0)"
                         : "=&v"(v0), "=&v"(v1) : "v"(upA), "v"(upB) : "memory");
            if (v0[3] >= tag && v1[3] >= tag) break;
            __builtin_amdgcn_s_sleep(1);
          }
          dstA[0] = v0[0]; dstA[1] = v0[1]; dstA[2] = v0[2];
          dstB[0] = v1[0]; dstB[1] = v1[1]; dstB[2] = v1[2];
        }
        __syncthreads();  // barrier B: h2s complete for next step
      } else {
        if (gate == 0) {
#pragma unroll
          for (int r = 0; r < 4; ++r)
            act[((size_t)(b0 + bg * 4 + r) * T_OUT + t) * HDIM + hcol] = h16[r];
        }
      }
    }
    if (gate == 0) {
#pragma unroll
      for (int r = 0; r < 4; ++r)
        cst[(size_t)(b0 + bg * 4 + r) * HDIM + hcol] = c_reg[r];
    }
  } else {
    // ================= GEMM worker branch =================
    if (!do_gemm) return;
    int wid = blockIdx.x - NLB;       // 0..191
    int sub = tid >> 8;               // 0..2 (wave-uniform)
    int stid = tid & 255;
    int tileid = wid + 192 * sub;     // 0..575
    bool valid = (tileid < NTILES);
    int tclamp = valid ? tileid : 0;
    int n0 = (tclamp % 12) * 128;
    int m0 = (tclamp / 12) * 128;
    f16x2* As2 = &sh.G.As2[sub][0];
    f16x2* Bs2 = &sh.G.Bs2[sub][0];
    int am = stid >> 2;
    int ak = (stid & 3) * 4;
    int bk = stid >> 5;
    int bn = (stid & 31) * 4;
    int row0 = m0 + am, row1 = row0 + 64;
    const f16* Ap0 = act + ((size_t)(row0 / TC) * T_OUT + lo_g + row0 % TC) * HDIM + ak;
    const f16* Ap1 = act + ((size_t)(row1 / TC) * T_OUT + lo_g + row1 % TC) * HDIM + ak;
    const float* Bp = Wi + (size_t)(2 * bk) * GDIM + n0 + bn;
    f16x4 ra0 = {}, ra1 = {};
    float4 rb0 = {}, rb1 = {};
    if (valid) {
      ra0 = *(const f16x4*)Ap0;
      ra1 = *(const f16x4*)Ap1;
      rb0 = *(const float4*)Bp;
      rb1 = *(const float4*)(Bp + (size_t)GDIM);
    }
    float acc[8][8];
#pragma unroll
    for (int i = 0; i < 8; ++i)
#pragma unroll
      for (int j = 0; j < 8; ++j) acc[i][j] = 0.f;
    int tx = stid & 15, ty = stid >> 4;
    for (int kt = 0; kt < 24; ++kt) {
      if (valid) {
        int ak2 = ak >> 1;
        As2[(ak2 + 0) * 136 + am] = (f16x2){ra0[0], ra0[1]};
        As2[(ak2 + 1) * 136 + am] = (f16x2){ra0[2], ra0[3]};
        As2[(ak2 + 0) * 136 + am + 64] = (f16x2){ra1[0], ra1[1]};
        As2[(ak2 + 1) * 136 + am + 64] = (f16x2){ra1[2], ra1[3]};
        Bs2[bk * 128 + bn + 0] = (f16x2){(f16)rb0.x, (f16)rb1.x};
        Bs2[bk * 128 + bn + 1] = (f16x2){(f16)rb0.y, (f16)rb1.y};
        Bs2[bk * 128 + bn + 2] = (f16x2){(f16)rb0.z, (f16)rb1.z};
        Bs2[bk * 128 + bn + 3] = (f16x2){(f16)rb0.w, (f16)rb1.w};
      }
      __syncthreads();
      if (valid) {
        if (kt < 23) {
          Ap0 += 16; Ap1 += 16; Bp += (size_t)16 * GDIM;
          ra0 = *(const f16x4*)Ap0;
          ra1 = *(const f16x4*)Ap1;
          rb0 = *(const float4*)Bp;
          rb1 = *(const float4*)(Bp + (size_t)GDIM);
        }
#pragma unroll
        for (int k2i = 0; k2i < 8; ++k2i) {
          f16x8 a0 = *(const f16x8*)&As2[k2i * 136 + ty * 4];
          f16x8 a1 = *(const f16x8*)&As2[k2i * 136 + 64 + ty * 4];
          f16x8 b0 = *(const f16x8*)&Bs2[k2i * 128 + tx * 4];
          f16x8 b1 = *(const f16x8*)&Bs2[k2i * 128 + 64 + tx * 4];
          f16x2 av[8], bv[8];
#pragma unroll
          for (int qq = 0; qq < 4; ++qq) {
            av[qq] = (f16x2){a0[2 * qq], a0[2 * qq + 1]};
            av[qq + 4] = (f16x2){a1[2 * qq], a1[2 * qq + 1]};
            bv[qq] = (f16x2){b0[2 * qq], b0[2 * qq + 1]};
            bv[qq + 4] = (f16x2){b1[2 * qq], b1[2 * qq + 1]};
          }
#pragma unroll
          for (int i = 0; i < 8; ++i)
#pragma unroll
            for (int j = 0; j < 8; ++j) acc[i][j] = fdot2(av[i], bv[j], acc[i][j]);
        }
      }
      __syncthreads();
    }
    if (valid) {
#pragma unroll
      for (int i = 0; i < 8; ++i) {
        int mi = (i < 4) ? (ty * 4 + i) : (64 + ty * 4 + i - 4);
        f16* Cp = xgc_wr + (size_t)(m0 + mi) * GDIM + n0;
        f16x4 p0, p1;
        p0[0] = (f16)acc[i][0]; p0[1] = (f16)acc[i][1]; p0[2] = (f16)acc[i][2]; p0[3] = (f16)acc[i][3];
        p1[0] = (f16)acc[i][4]; p1[1] = (f16)acc[i][5]; p1[2] = (f16)acc[i][6]; p1[3] = (f16)acc[i][7];
        *(f16x4*)(Cp + tx * 4) = p0;
        *(f16x4*)(Cp + 64 + tx * 4) = p1;
      }
    }
  }
}

// ---------------------------------------------------------------------------
// dense: out(204800,5) = h(204800,384 fp16) @ W(384,5) + b  (fp32 out)
// ---------------------------------------------------------------------------
__global__ __launch_bounds__(256) void dense_kernel(
    const f16* __restrict__ h, const float* __restrict__ dw,
    const float* __restrict__ db, float* __restrict__ out) {
  __shared__ float ws_[1920];
  __shared__ float bs[5];
  int tid = threadIdx.x;
  for (int i = tid; i < 1920; i += 256) ws_[i] = dw[i];
  if (tid < 5) bs[tid] = db[tid];
  __syncthreads();
  size_t flat = (size_t)blockIdx.x * 256 + tid;
  const f16* hp = h + flat * HDIM;
  float acc[5];
#pragma unroll
  for (int o = 0; o < 5; ++o) acc[o] = bs[o];
  for (int d = 0; d < HDIM; d += 4) {
    f16x4 hv = *(const f16x4*)(hp + d);
#pragma unroll
    for (int o = 0; o < 5; ++o) {
      acc[o] = fmaf((float)hv[0], ws_[(d + 0) * 5 + o], acc[o]);
      acc[o] = fmaf((float)hv[1], ws_[(d + 1) * 5 + o], acc[o]);
      acc[o] = fmaf((float)hv[2], ws_[(d + 2) * 5 + o], acc[o]);
      acc[o] = fmaf((float)hv[3], ws_[(d + 3) * 5 + o], acc[o]);
    }
  }
  float* op = out + flat * 5;
#pragma unroll
  for (int o = 0; o < 5; ++o) op[o] = acc[o];
}

// ---------------------------------------------------------------------------
extern "C" void kernel_launch(void* const* d_in, const int* in_sizes, int n_in,
                              void* d_out, int out_size, void* d_ws, size_t ws_size,
                              hipStream_t stream) {
  const float* x  = (const float*)d_in[0];
  const float* w1 = (const float*)d_in[1];
  const float* b1 = (const float*)d_in[2];
  const float* w2 = (const float*)d_in[3];
  const float* b2 = (const float*)d_in[4];
  const float* w3 = (const float*)d_in[5];
  const float* b3 = (const float*)d_in[6];
  const float* Wi = (const float*)d_in[7];
  const float* Wh = (const float*)d_in[8];
  const float* lb = (const float*)d_in[9];
  const float* dw = (const float*)d_in[10];
  const float* db = (const float*)d_in[11];
  float* out = (float*)d_out;
  char* ws = (char*)d_ws;

  // ws (~195.1 MB <= proven 197): act | xgcA | xgcB | whB | cst | xh
  const size_t ACT_BYTES = (size_t)B_SZ * T_OUT * HDIM * 2;   // 157.3 MB
  const size_t XGC_BYTES = (size_t)B_SZ * TC * GDIM * 2;      // 15.7 MB each
  const size_t WHB_BYTES = (size_t)5 * 8 * 12 * 12 * 64 * 16; // 5.9 MB
  const size_t CST_BYTES = (size_t)B_SZ * HDIM * 4;           // 196.6 KB
  const size_t XH_BYTES  = (size_t)2 * 128 * 64 * 16;         // 256 KB
  f16*      act  = (f16*)ws;
  f16*      xgcA = (f16*)(ws + ACT_BYTES);
  f16*      xgcB = (f16*)(ws + ACT_BYTES + XGC_BYTES);
  f16*      whB  = (f16*)(ws + ACT_BYTES + 2 * XGC_BYTES);
  float*    cst  = (float*)(ws + ACT_BYTES + 2 * XGC_BYTES + WHB_BYTES);
  unsigned* xh   = (unsigned*)(ws + ACT_BYTES + 2 * XGC_BYTES + WHB_BYTES + CST_BYTES);
  f16* y2 = xgcA;  // alias: consumed before xgc/whB are written

  hipMemsetAsync(xh, 0, XH_BYTES, stream);  // zero tags (monotonic from 1)

  hipLaunchKernelGGL(conv12_kernel, dim3(B_SZ * T_IN / 256), dim3(256), 0, stream,
                     x, w1, b1, w2, b2, y2);
  hipLaunchKernelGGL(conv3_kernel, dim3(T_OUT / 16, B_SZ), dim3(384), 0, stream,
                     y2, w3, b3, act);
  hipLaunchKernelGGL(whcvt_kernel, dim3((unsigned)(WHB_BYTES / 4 / 256)), dim3(256), 0, stream,
                     Wh, (f16x2*)whB);

  for (int l = 0; l < 5; ++l) {
    int rev = (l % 2 == 0) ? 1 : 0;
    const float* wi_p = Wi + (size_t)l * HDIM * GDIM;
    const f16* wh_p = whB + (size_t)l * 8 * 12 * 12 * 64 * 8;
    const float* lb_p = lb + (size_t)l * GDIM;
    int lo0 = rev ? (T_OUT - TC) : 0;
    hipLaunchKernelGGL(gemm_xg_kernel, dim3(GDIM / 128, (B_SZ * TC) / 128), dim3(256), 0, stream,
                       act, wi_p, xgcA, lo0);
    for (int ci = 0; ci < NCHUNK; ++ci) {
      int lo_l = rev ? (T_OUT - (ci + 1) * TC) : (ci * TC);
      int do_gemm = (ci + 1 < NCHUNK) ? 1 : 0;
      int lo_g = do_gemm ? (rev ? (T_OUT - (ci + 2) * TC) : ((ci + 1) * TC)) : 0;
      f16* rd = (ci % 2 == 0) ? xgcA : xgcB;
      f16* wr = (ci % 2 == 0) ? xgcB : xgcA;
      int epoch = l * NCHUNK + ci;
      hipLaunchKernelGGL(fused_kernel, dim3(256), dim3(768), 0, stream,
                         rd, wr, wh_p, lb_p, act, cst, wi_p, xh,
                         lo_l, lo_g, rev, (ci == 0) ? 1 : 0, do_gemm, epoch);
    }
  }
  hipLaunchKernelGGL(dense_kernel, dim3((B_SZ * T_OUT) / 256), dim3(256), 0, stream,
                     act, dw, db, out);
}